// Round 4
// baseline (3261.738 us; speedup 1.0000x reference)
//
#include <hip/hip_runtime.h>
#include <math.h>

#define BB 48
#define NN 96
#define EE 1024
#define DD 300
#define LL 4
#define G3 900          // 3*D
#define PP 150          // DD/2 f16 pairs
#define PP2 152         // padded pairs (38 chunks of 4)
#define NC4 38          // weight chunks of 4 pairs
#define HDIM 3724       // D*(2L+1)+E
#define ROWS (BB*NN)    // 4608
#define NEGI -1.0e30f
#define KP300 304       // 300 padded to mult-of-8
#define GIC_TILES 540   // 15 x 36 tiles for fused GIc GEMM

#define NPF  12         // pwi chunks prefetched into regs each step (48 VGPRs, short-lived)
#define NLDS 5          // pwi chunks resident in LDS (72000 B), chunk ids 12..16
// streamed chunks in phase D: 17..37 (21 chunks)

typedef _Float16 half2_t __attribute__((ext_vector_type(2)));
typedef _Float16 h8 __attribute__((ext_vector_type(8)));
typedef float f4 __attribute__((ext_vector_type(4)));

__device__ __forceinline__ float sigm(float x){
    return __fdividef(1.0f, 1.0f + __expf(-x));
}
__device__ __forceinline__ float ftanh(float x){
    // 1 - 2/(e^{2x}+1); exact limits at +-inf via v_exp saturation
    float e = __expf(2.0f*x);
    return 1.0f - __fdividef(2.0f, e + 1.0f);
}

__device__ __forceinline__ void dot4(const h8 wv, const h8 mc,
                                     float& a0, float& a1, float& a2, float& a3)
{
    half2_t w0,w1,w2,w3,m0,m1,m2,m3;
    w0.x=wv[0]; w0.y=wv[1]; m0.x=mc[0]; m0.y=mc[1];
    w1.x=wv[2]; w1.y=wv[3]; m1.x=mc[2]; m1.y=mc[3];
    w2.x=wv[4]; w2.y=wv[5]; m2.x=mc[4]; m2.y=mc[5];
    w3.x=wv[6]; w3.y=wv[7]; m3.x=mc[6]; m3.y=mc[7];
    a0 = __builtin_amdgcn_fdot2(w0, m0, a0, false);
    a1 = __builtin_amdgcn_fdot2(w1, m1, a1, false);
    a2 = __builtin_amdgcn_fdot2(w2, m2, a2, false);
    a3 = __builtin_amdgcn_fdot2(w3, m3, a3, false);
}

// ---------------- pack W (L,900,300) -> coalesced h8 chunks (L,38,900) ----------------
__global__ __launch_bounds__(256) void pack_w_q(const float* __restrict__ src_all,
                                                h8* __restrict__ dst)
{
    int l = blockIdx.y;
    int idx = blockIdx.x*256 + threadIdx.x;
    if (idx >= NC4*G3) return;
    int c = idx / G3, gate = idx % G3;
    const float* src = src_all + (size_t)l*G3*DD + (size_t)gate*DD;
    h8 v;
    #pragma unroll
    for (int j=0;j<8;j++){
        int d = 8*c + j;
        v[j] = (d<DD) ? (_Float16)src[d] : (_Float16)0.f;
    }
    dst[(size_t)l*NC4*G3 + idx] = v;
}

// ---------------- GRU weights [900][300] fp32 -> [900][304] f16 (zero-padded) ----------------
__global__ __launch_bounds__(256) void conv_gru_w(const float* __restrict__ gp_whh,
                                                  const float* __restrict__ gc_wih,
                                                  const float* __restrict__ gc_whh,
                                                  _Float16* __restrict__ outp)
{
    int z = blockIdx.y; int l = z/3, wsel = z%3;
    const float* src = (wsel==0?gp_whh:wsel==1?gc_wih:gc_whh) + (size_t)l*G3*DD;
    _Float16* dst = outp + (size_t)z*G3*KP300;
    int idx = blockIdx.x*256 + threadIdx.x;
    if (idx >= G3*KP300) return;
    int n = idx/KP300, k = idx%KP300;
    dst[idx] = (k<DD) ? (_Float16)src[(size_t)n*DD+k] : (_Float16)0.f;
}

// ---------------- transpose-convert [K][N] fp32 -> [N][Kpad] f16 ----------------
__global__ __launch_bounds__(256) void convT(const float* __restrict__ src,
                                             _Float16* __restrict__ dst,
                                             int K, int N, int Kpad)
{
    int idx = blockIdx.x*256 + threadIdx.x;
    if (idx >= N*Kpad) return;
    int n = idx/Kpad, k = idx%Kpad;
    dst[idx] = (k<K) ? (_Float16)src[(size_t)k*N + n] : (_Float16)0.f;
}

// ---------------- MFMA f16 GEMM tile body (device fn, 256 active threads) ----------------
__device__ __forceinline__ void gemm_tile(
    int m0, int n0, int tid,
    const float* __restrict__ A, int lda,
    const _Float16* __restrict__ B, int Kpad,
    const float* __restrict__ bias,
    float* __restrict__ C, int ldc,
    int N, int K, int relu,
    _Float16 (*As)[40], _Float16 (*Bs)[40])
{
    int w = tid>>6, lane = tid&63;
    int wy = w>>1, wx = w&1;
    int lm = lane&15, q = lane>>4;

    f4 acc[4][2];
    #pragma unroll
    for (int a=0;a<4;a++)
        #pragma unroll
        for (int b=0;b<2;b++)
            #pragma unroll
            for (int r=0;r<4;r++) acc[a][b][r]=0.f;

    int am = tid>>1, akg = (tid&1)*16;
    int bn = tid>>2, bkg = (tid&3)*8;
    const float* arow = A + (size_t)(m0+am)*lda;

    for (int k0=0; k0<K; k0+=32){
        {
            __align__(16) _Float16 av[16];
            #pragma unroll
            for (int u=0;u<16;u+=4){
                int k = k0 + akg + u;
                float x0,x1,x2,x3;
                if (k+4 <= K){
                    float4 v = *(const float4*)(arow + k);
                    x0=v.x;x1=v.y;x2=v.z;x3=v.w;
                } else {
                    x0 = (k  <K)? arow[k  ]:0.f;
                    x1 = (k+1<K)? arow[k+1]:0.f;
                    x2 = (k+2<K)? arow[k+2]:0.f;
                    x3 = (k+3<K)? arow[k+3]:0.f;
                }
                av[u]=(_Float16)x0; av[u+1]=(_Float16)x1;
                av[u+2]=(_Float16)x2; av[u+3]=(_Float16)x3;
            }
            *(h8*)&As[am][akg]   = *(h8*)&av[0];
            *(h8*)&As[am][akg+8] = *(h8*)&av[8];
        }
        {
            int gk = k0 + bkg;
            h8 bv;
            #pragma unroll
            for (int j=0;j<8;j++) bv[j]=(_Float16)0.f;
            if (n0+bn < N && gk < Kpad)
                bv = *(const h8*)(B + (size_t)(n0+bn)*Kpad + gk);
            *(h8*)&Bs[bn][bkg] = bv;
        }
        __syncthreads();
        h8 af[4], bf[2];
        #pragma unroll
        for (int mb=0; mb<4; mb++) af[mb] = *(h8*)&As[wy*64+mb*16+lm][q*8];
        #pragma unroll
        for (int nb=0; nb<2; nb++) bf[nb] = *(h8*)&Bs[wx*32+nb*16+lm][q*8];
        #pragma unroll
        for (int mb=0; mb<4; mb++)
            #pragma unroll
            for (int nb=0; nb<2; nb++)
                acc[mb][nb] = __builtin_amdgcn_mfma_f32_16x16x32_f16(af[mb], bf[nb], acc[mb][nb], 0,0,0);
        __syncthreads();
    }
    #pragma unroll
    for (int mb=0; mb<4; mb++){
        int r0 = m0 + wy*64 + mb*16 + q*4;
        #pragma unroll
        for (int nb=0; nb<2; nb++){
            int c = n0 + wx*32 + nb*16 + lm;
            if (c < N){
                float bb = bias[c];
                #pragma unroll
                for (int reg=0; reg<4; reg++){
                    float v = acc[mb][nb][reg] + bb;
                    if (relu) v = fmaxf(v, 0.f);
                    C[(size_t)(r0+reg)*ldc + c] = v;
                }
            }
        }
    }
}

// ---------------- standalone MFMA GEMM kernel ----------------
__global__ __launch_bounds__(256) void gemm_mfma(
    const float* __restrict__ A, int lda,
    const _Float16* __restrict__ B, int Kpad,
    const float* __restrict__ bias,
    float* __restrict__ C, int ldc,
    int N, int K, int relu)
{
    __shared__ _Float16 As[128][40];
    __shared__ _Float16 Bs[64][40];
    gemm_tile(blockIdx.y*128, blockIdx.x*64, threadIdx.x,
              A, lda, B, Kpad, bias, C, ldc, N, K, relu, As, Bs);
}

// ---------------- copy features into last 1024 cols of Hbuf ----------------
__global__ void featcopy(const float* __restrict__ f, float* __restrict__ H)
{
    size_t row = blockIdx.x;
    int t = threadIdx.x;
    float4 v = *(const float4*)(f + row*EE + t*4);
    *(float4*)(H + row*HDIM + 2700 + t*4) = v;
}

// ---------------- fused scan + GIc GEMM ----------------
// blocks 0..47: sequential p-scan. blocks 48..587: GIc GEMM tiles.
// Round-0 5-phase structure. Phase-D weight supply: 12 chunks PREFETCHED into
// registers at the top of each step (issue hidden under softmax+C+Csum; asm
// anchor prevents sinking), 5 chunks resident in LDS (loaded once), 21 streamed
// in-phase. No long-lived register pinning (2x proven to spill to scratch).
// Fast transcendentals (__expf/__fdividef) in softmax + GRU phases.
__global__ __launch_bounds__(1024, 4) void scan_kernel(
    float* __restrict__ Hbuf,
    const float* __restrict__ GHp,
    const h8* __restrict__ pwiQ,          // (38,900) h8 chunks of pwi
    const h8* __restrict__ pwhQ,          // (38,900) h8 chunks of pwh (init)
    const float* __restrict__ pbi,
    const float* __restrict__ pbh,
    const float* __restrict__ wk,
    const float* __restrict__ wq,
    const float* __restrict__ gat_b, int lidx,
    const float* __restrict__ adj,
    float* __restrict__ Mbuf,
    int ccol, int hcol, int pcol,
    const _Float16* __restrict__ cwiF,
    const float* __restrict__ cbi,
    float* __restrict__ GIc)
{
    __shared__ __align__(16) char pool[146432];

    // ---- GEMM blocks (LDS pool reused as As/Bs) ----
    if (blockIdx.x >= BB){
        if (threadIdx.x < 256){
            _Float16 (*As)[40] = (_Float16 (*)[40])pool;
            _Float16 (*Bs)[40] = (_Float16 (*)[40])(pool + 128*40*2);
            int bid = blockIdx.x - BB;
            int n0 = (bid % 15)*64, m0 = (bid / 15)*128;
            gemm_tile(m0, n0, threadIdx.x, Hbuf + ccol, HDIM, cwiF, KP300,
                      cbi, GIc, G3, G3, DD, 0, As, Bs);
        }
        return;
    }

    int b = blockIdx.x;
    int t = threadIdx.x;

    // ---- LDS pool carve-up (all offsets 16B aligned) ----
    half2_t (*P_h2)[PP]   = (half2_t (*)[PP])(pool);             //  57600
    h8*      Wlds         = (h8*)(pool + 57600);                 //  72000 (5 chunks)
    float*   g_s          = (float*)(pool + 129600);             //   3600
    float  (*Mpart)[DD]   = (float (*)[DD])(pool + 133200);      //   3600
    float*   ghp_s        = (float*)(pool + 136800);             //   3600
    float*   hv_s         = (float*)(pool + 140400);             //   1200
    float*   pw_s         = (float*)(pool + 141600);             //   1200
    half2_t* M_h2         = (half2_t*)(pool + 142800);           //    608
    float*   e_s          = (float*)(pool + 143424);             //    384
    float*   pk_s         = (float*)(pool + 143808);             //    384
    float*   qd_s         = (float*)(pool + 144192);             //    384
    unsigned (*adjb)[4]   = (unsigned (*)[4])(pool + 144576);    //   1536 -> 146112

    size_t rowbase = (size_t)b*NN;

    float pbi_r = (t < G3) ? pbi[t] : 0.f;
    float2 wk_r = make_float2(0.f,0.f);
    if (t < PP) wk_r = *(const float2*)&wk[2*t];

    // ---- init phase 1: LDS weight chunks + adj bitmask + qdot + Cin0 -> M
    for (int idx=t; idx<NLDS*G3; idx+=1024)
        Wlds[idx] = pwiQ[(size_t)(NPF + idx/G3)*G3 + (idx%G3)];
    if (t < NN*3){
        int r = t/3, w = t%3;
        const float* arow = adj + (rowbase + r)*NN + w*32;
        unsigned m = 0;
        for (int c=0;c<32;c++) if (arow[c] != 0.f) m |= (1u<<c);
        adjb[r][w] = m;
    }
    {
        int w = t>>6, lane = t&63;
        float gb = gat_b[lidx];
        for (int r = w; r < NN; r += 16){
            const float* x = Hbuf + (rowbase + r)*HDIM + ccol;
            float s = 0.f;
            for (int d=lane; d<DD; d+=64) s += x[d]*wq[d];
            #pragma unroll
            for (int o=32;o>0;o>>=1) s += __shfl_xor(s,o);
            if (lane==0) qd_s[r] = s + gb;
        }
    }
    if (t < PP){
        float2 c2 = *(const float2*)&Hbuf[rowbase*HDIM + ccol + 2*t];
        Mpart[0][2*t] = c2.x; Mpart[0][2*t+1] = c2.y;
        half2_t mh; mh.x = (_Float16)c2.x; mh.y = (_Float16)c2.y;
        M_h2[t] = mh;
    } else if (t < PP2){
        half2_t z; z.x=(_Float16)0.f; z.y=(_Float16)0.f;
        M_h2[t] = z;
    }
    __syncthreads();
    // ---- init phase 2: gh0 = Cin0 @ pwh^T + pbh
    if (t < G3){
        const h8* W2 = pwhQ + t;
        float a0=0.f, a1=0.f, a2=0.f, a3=0.f;
        #pragma unroll 4
        for (int c=0;c<NC4;c++){
            h8 wv = W2[(size_t)c*G3];
            h8 mc = *(h8*)&M_h2[4*c];
            dot4(wv, mc, a0,a1,a2,a3);
        }
        g_s[t] = pbh[t] + (a0+a2) + (a1+a3);
    }
    __syncthreads();
    // ---- init phase 3: p0 = GRU(x=0, h=Cin0); M[b,0]=0
    if (t < PP){
        int d0 = 2*t, d1 = 2*t+1;
        float r0  = sigm(pbi[d0]      + g_s[d0]);
        float z0  = sigm(pbi[DD+d0]   + g_s[DD+d0]);
        float n0  = ftanh(pbi[2*DD+d0] + r0*g_s[2*DD+d0]);
        float p0  = (1.f-z0)*n0 + z0*Mpart[0][d0];
        float r1  = sigm(pbi[d1]      + g_s[d1]);
        float z1  = sigm(pbi[DD+d1]   + g_s[DD+d1]);
        float n1  = ftanh(pbi[2*DD+d1] + r1*g_s[2*DD+d1]);
        float p1  = (1.f-z1)*n1 + z1*Mpart[0][d1];
        *(float2*)&Hbuf[rowbase*HDIM + pcol + d0] = make_float2(p0,p1);
        half2_t ph; ph.x = (_Float16)p0; ph.y = (_Float16)p1;
        P_h2[0][t] = ph;
        pw_s[d0] = p0*wk_r.x;
        pw_s[d1] = p1*wk_r.y;
        *(float2*)&Mbuf[rowbase*DD + d0] = make_float2(0.f,0.f);
    }
    __syncthreads();

    for (int i=1;i<NN;i++){
        size_t row = rowbase + i;

        // ---- prefetch 12 weight chunks for phase D; issue NOW so the L2
        // latency hides under AB+C+Csum. asm anchor: loads can't sink past it.
        h8 pf0,pf1,pf2,pf3,pf4,pf5,pf6,pf7,pf8,pf9,pf10,pf11;
        if (t < G3){
            const h8* W = pwiQ + t;
            pf0 = W[0];             pf1 = W[(size_t)1*G3];  pf2 = W[(size_t)2*G3];
            pf3 = W[(size_t)3*G3];  pf4 = W[(size_t)4*G3];  pf5 = W[(size_t)5*G3];
            pf6 = W[(size_t)6*G3];  pf7 = W[(size_t)7*G3];  pf8 = W[(size_t)8*G3];
            pf9 = W[(size_t)9*G3];  pf10 = W[(size_t)10*G3]; pf11 = W[(size_t)11*G3];
            asm volatile("" : "+v"(pf0),"+v"(pf1),"+v"(pf2),"+v"(pf3),"+v"(pf4),"+v"(pf5));
            asm volatile("" : "+v"(pf6),"+v"(pf7),"+v"(pf8),"+v"(pf9),"+v"(pf10),"+v"(pf11));
        }

        // ---- AB (wave 0): pk reduce + logits + softmax (adj via bitmask)
        if (t < 64){
            float s = 0.f;
            for (int c=t;c<DD;c+=64) s += pw_s[c];
            #pragma unroll
            for (int o=32;o>0;o>>=1) s += __shfl_xor(s,o);
            if (t==0) pk_s[i-1] = s;
            float q = qd_s[i];
            float a0 = NEGI, a1 = NEGI;
            if (t < i){
                if ((adjb[i][t>>5]>>(t&31))&1u) a0 = q + ((t==i-1)? s : pk_s[t]);
            }
            int j1 = 64+t;
            if (t < 32 && j1 < i){
                if ((adjb[i][2]>>t)&1u) a1 = q + ((j1==i-1)? s : pk_s[j1]);
            }
            float m = fmaxf(a0,a1);
            #pragma unroll
            for (int o=32;o>0;o>>=1) m = fmaxf(m, __shfl_xor(m,o));
            float e0 = __expf(a0-m);
            float e1 = (t<32)? __expf(a1-m) : 0.f;
            float ss = e0+e1;
            #pragma unroll
            for (int o=32;o>0;o>>=1) ss += __shfl_xor(ss,o);
            float inv = __fdividef(1.f, ss);
            e_s[t] = e0*inv;
            if (t<32) e_s[64+t] = e1*inv;
        }
        __syncthreads();
        // ---- C (t<450): 3-way j-split weighted sum; prefetchers (t>=512)
        if (t < 450){
            int g = t/150, dp = t%150;
            int cnt = (i+2)/3;
            int j0 = g*cnt; int j1 = j0+cnt; if (j1 > i) j1 = i;
            float m0=0.f, m1=0.f;
            for (int j=j0;j<j1;j++){
                float w = e_s[j];
                half2_t pv = P_h2[j][dp];
                m0 += w*(float)pv.x;
                m1 += w*(float)pv.y;
            }
            *(float2*)&Mpart[g][2*dp] = make_float2(m0,m1);
        } else if (t >= 512){
            int k = t-512;
            #pragma unroll
            for (int it=0; it<2; it++){
                int idx = k + it*512;
                if (idx < 450){
                    *(float2*)&ghp_s[2*idx] = *(const float2*)&GHp[row*G3 + 2*idx];
                } else if (idx < 600){
                    int h = idx-450;
                    *(float2*)&hv_s[2*h] = *(const float2*)&Hbuf[row*HDIM + hcol + 2*h];
                }
            }
        }
        __syncthreads();
        // ---- Csum (t<150): combine partials, write Mbuf + f16 M
        if (t < PP){
            float m0 = Mpart[0][2*t] + Mpart[1][2*t] + Mpart[2][2*t];
            float m1 = Mpart[0][2*t+1] + Mpart[1][2*t+1] + Mpart[2][2*t+1];
            half2_t mh; mh.x = (_Float16)m0; mh.y = (_Float16)m1;
            M_h2[t] = mh;
            *(float2*)&Mbuf[row*DD + 2*t] = make_float2(m0,m1);
        }
        __syncthreads();
        // ---- D (t<900): g = M @ pwi^T + pbi; 12 prefetched + 5 LDS + 21 streamed
        if (t < G3){
            const h8* W = pwiQ + t;
            const h8* Mc = (const h8*)M_h2;
            float a0=0.f, a1=0.f, a2=0.f, a3=0.f;
            dot4(pf0,  Mc[0],  a0,a1,a2,a3);
            dot4(pf1,  Mc[1],  a0,a1,a2,a3);
            dot4(pf2,  Mc[2],  a0,a1,a2,a3);
            dot4(pf3,  Mc[3],  a0,a1,a2,a3);
            dot4(pf4,  Mc[4],  a0,a1,a2,a3);
            dot4(pf5,  Mc[5],  a0,a1,a2,a3);
            dot4(pf6,  Mc[6],  a0,a1,a2,a3);
            dot4(pf7,  Mc[7],  a0,a1,a2,a3);
            dot4(pf8,  Mc[8],  a0,a1,a2,a3);
            dot4(pf9,  Mc[9],  a0,a1,a2,a3);
            dot4(pf10, Mc[10], a0,a1,a2,a3);
            dot4(pf11, Mc[11], a0,a1,a2,a3);
            dot4(Wlds[t],        Mc[NPF+0], a0,a1,a2,a3);
            dot4(Wlds[G3+t],     Mc[NPF+1], a0,a1,a2,a3);
            dot4(Wlds[2*G3+t],   Mc[NPF+2], a0,a1,a2,a3);
            dot4(Wlds[3*G3+t],   Mc[NPF+3], a0,a1,a2,a3);
            dot4(Wlds[4*G3+t],   Mc[NPF+4], a0,a1,a2,a3);
            #pragma unroll 4
            for (int c=NPF+NLDS;c<NC4;c++){
                h8 wv = W[(size_t)c*G3];
                dot4(wv, Mc[c], a0,a1,a2,a3);
            }
            g_s[t] = pbi_r + (a0+a2) + (a1+a3);
        }
        __syncthreads();
        // ---- E (t<150): GRU combine (pure LDS), write P row + pw
        if (t < PP){
            int d0 = 2*t, d1 = 2*t+1;
            float2 hv = *(const float2*)&hv_s[d0];
            float r0  = sigm(g_s[d0]      + ghp_s[d0]);
            float z0  = sigm(g_s[DD+d0]   + ghp_s[DD+d0]);
            float n0  = ftanh(g_s[2*DD+d0] + r0*ghp_s[2*DD+d0]);
            float p0  = (1.f-z0)*n0 + z0*hv.x;
            float r1  = sigm(g_s[d1]      + ghp_s[d1]);
            float z1  = sigm(g_s[DD+d1]   + ghp_s[DD+d1]);
            float n1  = ftanh(g_s[2*DD+d1] + r1*ghp_s[2*DD+d1]);
            float p1  = (1.f-z1)*n1 + z1*hv.y;
            *(float2*)&Hbuf[row*HDIM + pcol + d0] = make_float2(p0,p1);
            half2_t ph; ph.x = (_Float16)p0; ph.y = (_Float16)p1;
            P_h2[i][t] = ph;
            pw_s[d0] = p0*wk_r.x;
            pw_s[d1] = p1*wk_r.y;
        }
        __syncthreads();
    }
}

// ---------------- c-side elementwise combine ----------------
__global__ __launch_bounds__(320) void combine_c(
    const float* __restrict__ GIc, const float* __restrict__ GHc,
    const float* __restrict__ Mbuf, float* __restrict__ Hbuf, int clcol)
{
    size_t row = blockIdx.x;
    int d = threadIdx.x;
    if (d < DD){
        float ir = GIc[row*G3+d], iz = GIc[row*G3+DD+d], inn = GIc[row*G3+2*DD+d];
        float hr = GHc[row*G3+d], hz = GHc[row*G3+DD+d], hn  = GHc[row*G3+2*DD+d];
        float r  = sigm(ir+hr);
        float z  = sigm(iz+hz);
        float nn = ftanh(inn + r*hn);
        float h  = Mbuf[row*DD+d];
        Hbuf[row*HDIM + clcol + d] = (1.f-z)*nn + z*h;
    }
}

// ---------------- logits: out = x2 @ w2 + b2 (N=7) ----------------
__global__ __launch_bounds__(64) void logits_kernel(
    const float* __restrict__ x2, const float* __restrict__ w2,
    const float* __restrict__ b2, float* __restrict__ out)
{
    size_t row = blockIdx.x;
    int lane = threadIdx.x;
    float acc[7]={0,0,0,0,0,0,0};
    for (int d=lane; d<DD; d+=64){
        float x = x2[row*DD+d];
        #pragma unroll
        for (int c=0;c<7;c++) acc[c] += x*w2[d*7+c];
    }
    #pragma unroll
    for (int c=0;c<7;c++){
        float s = acc[c];
        #pragma unroll
        for (int o=32;o>0;o>>=1) s += __shfl_down(s,o);
        if (lane==0) out[row*7+c] = s + b2[c];
    }
}

extern "C" void kernel_launch(void* const* d_in, const int* in_sizes, int n_in,
                              void* d_out, int out_size, void* d_ws, size_t ws_size,
                              hipStream_t stream)
{
    const float* features = (const float*)d_in[0];
    const float* adj      = (const float*)d_in[1];
    const float* fc1_w    = (const float*)d_in[3];
    const float* fc1_b    = (const float*)d_in[4];
    const float* gc_wih   = (const float*)d_in[5];
    const float* gc_whh   = (const float*)d_in[6];
    const float* gc_bih   = (const float*)d_in[7];
    const float* gc_bhh   = (const float*)d_in[8];
    const float* gp_wih   = (const float*)d_in[9];
    const float* gp_whh   = (const float*)d_in[10];
    const float* gp_bih   = (const float*)d_in[11];
    const float* gp_bhh   = (const float*)d_in[12];
    const float* gat_wq   = (const float*)d_in[13];
    const float* gat_wk   = (const float*)d_in[14];
    const float* gat_b    = (const float*)d_in[15];
    const float* mlp_w0   = (const float*)d_in[16];
    const float* mlp_b0   = (const float*)d_in[17];
    const float* mlp_w1   = (const float*)d_in[18];
    const float* mlp_b1   = (const float*)d_in[19];
    const float* mlp_w2   = (const float*)d_in[20];
    const float* mlp_b2   = (const float*)d_in[21];
    float* out = (float*)d_out;

    float* ws = (float*)d_ws;
    size_t off = 0;
    float* Hbuf = ws + off; off += (size_t)ROWS*HDIM;
    float* bufA = ws + off; off += (size_t)ROWS*G3;    // GHp
    float* bufB = ws + off; off += (size_t)ROWS*G3;    // GIc / x1
    float* bufC = ws + off; off += (size_t)ROWS*G3;    // GHc / x2
    float* Mbuf = ws + off; off += (size_t)ROWS*DD;
    h8* pwiQ = (h8*)(ws + off); off += (size_t)LL*NC4*G3*4;
    h8* pwhQ = (h8*)(ws + off); off += (size_t)LL*NC4*G3*4;
    _Float16* gruF = (_Float16*)(ws + off); off += (size_t)12*G3*KP300/2;
    _Float16* fc1F = (_Float16*)(ws + off); off += (size_t)DD*EE/2;
    _Float16* mlp0F= (_Float16*)(ws + off); off += (size_t)DD*3728/2;
    _Float16* mlp1F= (_Float16*)(ws + off); off += (size_t)DD*KP300/2;
    (void)ws_size; (void)in_sizes; (void)n_in; (void)out_size;

    // 1. weight prep
    {
        pack_w_q<<<dim3((NC4*G3+255)/256, LL), 256, 0, stream>>>(gp_wih, pwiQ);
        pack_w_q<<<dim3((NC4*G3+255)/256, LL), 256, 0, stream>>>(gp_whh, pwhQ);
        conv_gru_w<<<dim3((G3*KP300+255)/256, 12), 256, 0, stream>>>(gp_whh, gc_wih, gc_whh, gruF);
        convT<<<(DD*EE+255)/256, 256, 0, stream>>>(fc1_w, fc1F, EE, DD, EE);
        convT<<<(DD*3728+255)/256, 256, 0, stream>>>(mlp_w0, mlp0F, HDIM, DD, 3728);
        convT<<<(DD*KP300+255)/256, 256, 0, stream>>>(mlp_w1, mlp1F, DD, DD, KP300);
    }
    // 2. H0 = relu(features @ fc1_w + fc1_b) -> Hbuf col 0
    gemm_mfma<<<dim3(5,36),256,0,stream>>>(features, EE, fc1F, EE, fc1_b,
                                           Hbuf, HDIM, DD, EE, 1);
    // 3. features -> Hbuf cols [2700,3724)
    featcopy<<<ROWS,256,0,stream>>>(features, Hbuf);

    for (int l=0;l<LL;l++){
        int ccol  = (l==0)? 0 : 300 + (l-1)*600;
        int hcol  = l*300;
        int pcol  = 600 + l*600;
        int clcol = 300 + l*600;
        const h8* pwiQl = pwiQ + (size_t)l*NC4*G3;
        const h8* pwhQl = pwhQ + (size_t)l*NC4*G3;
        const _Float16* pwhF = gruF + (size_t)(l*3+0)*G3*KP300;
        const _Float16* cwiF = gruF + (size_t)(l*3+1)*G3*KP300;
        const _Float16* cwhF = gruF + (size_t)(l*3+2)*G3*KP300;

        // GHp = Hin @ pwh^T + pbh
        gemm_mfma<<<dim3(15,36),256,0,stream>>>(Hbuf+hcol, HDIM, pwhF, KP300,
                                                gp_bhh + l*G3, bufA, G3, G3, DD, 0);
        // fused: scan (blocks 0..47) + GIc GEMM (blocks 48..587)
        scan_kernel<<<BB+GIC_TILES,1024,0,stream>>>(Hbuf, bufA, pwiQl, pwhQl,
                                          gp_bih + l*G3, gp_bhh + l*G3,
                                          gat_wk + l*DD, gat_wq + l*DD, gat_b, l,
                                          adj, Mbuf, ccol, hcol, pcol,
                                          cwiF, gc_bih + l*G3, bufB);
        // GHc = M @ cwh^T + cbh
        gemm_mfma<<<dim3(15,36),256,0,stream>>>(Mbuf, DD, cwhF, KP300,
                                                gc_bhh + l*G3, bufC, G3, G3, DD, 0);
        // CL = GRU-combine
        combine_c<<<ROWS,320,0,stream>>>(bufB, bufC, Mbuf, Hbuf, clcol);
    }

    // MLP
    gemm_mfma<<<dim3(5,36),256,0,stream>>>(Hbuf, HDIM, mlp0F, 3728, mlp_b0,
                                           bufB, DD, DD, HDIM, 1);
    gemm_mfma<<<dim3(5,36),256,0,stream>>>(bufB, DD, mlp1F, KP300, mlp_b1,
                                           bufC, DD, DD, DD, 1);
    logits_kernel<<<ROWS,64,0,stream>>>(bufC, mlp_w2, mlp_b2, out);
}

// Round 5
// 3016.533 us; speedup vs baseline: 1.0813x; 1.0813x over previous
//
#include <hip/hip_runtime.h>
#include <math.h>

#define BB 48
#define NN 96
#define EE 1024
#define DD 300
#define LL 4
#define G3 900          // 3*D
#define PP 150          // DD/2 f16 pairs
#define PP2 152         // padded pairs (38 chunks of 4)
#define NC4 38          // weight chunks of 4 pairs
#define HDIM 3724       // D*(2L+1)+E
#define ROWS (BB*NN)    // 4608
#define NEGI -1.0e30f
#define KP300 304       // 300 padded to mult-of-8
#define GIC_TILES 540   // 15 x 36 tiles for fused GIc GEMM

#define NLDS 6          // pwi chunks resident in LDS (86400 B), ids 0..5
// streamed chunks in phase D: 6..37 (32 chunks, unroll 8 -> 4 clean groups)

typedef _Float16 half2_t __attribute__((ext_vector_type(2)));
typedef _Float16 h8 __attribute__((ext_vector_type(8)));
typedef float f4 __attribute__((ext_vector_type(4)));

__device__ __forceinline__ float sigm(float x){
    return __fdividef(1.0f, 1.0f + __expf(-x));
}
__device__ __forceinline__ float ftanh(float x){
    float e = __expf(2.0f*x);
    return 1.0f - __fdividef(2.0f, e + 1.0f);
}

__device__ __forceinline__ void dot4(const h8 wv, const h8 mc,
                                     float& a0, float& a1, float& a2, float& a3)
{
    half2_t w0,w1,w2,w3,m0,m1,m2,m3;
    w0.x=wv[0]; w0.y=wv[1]; m0.x=mc[0]; m0.y=mc[1];
    w1.x=wv[2]; w1.y=wv[3]; m1.x=mc[2]; m1.y=mc[3];
    w2.x=wv[4]; w2.y=wv[5]; m2.x=mc[4]; m2.y=mc[5];
    w3.x=wv[6]; w3.y=wv[7]; m3.x=mc[6]; m3.y=mc[7];
    a0 = __builtin_amdgcn_fdot2(w0, m0, a0, false);
    a1 = __builtin_amdgcn_fdot2(w1, m1, a1, false);
    a2 = __builtin_amdgcn_fdot2(w2, m2, a2, false);
    a3 = __builtin_amdgcn_fdot2(w3, m3, a3, false);
}

// ---------------- pack W (L,900,300) -> coalesced h8 chunks (L,38,900) ----------------
__global__ __launch_bounds__(256) void pack_w_q(const float* __restrict__ src_all,
                                                h8* __restrict__ dst)
{
    int l = blockIdx.y;
    int idx = blockIdx.x*256 + threadIdx.x;
    if (idx >= NC4*G3) return;
    int c = idx / G3, gate = idx % G3;
    const float* src = src_all + (size_t)l*G3*DD + (size_t)gate*DD;
    h8 v;
    #pragma unroll
    for (int j=0;j<8;j++){
        int d = 8*c + j;
        v[j] = (d<DD) ? (_Float16)src[d] : (_Float16)0.f;
    }
    dst[(size_t)l*NC4*G3 + idx] = v;
}

// ---------------- GRU weights [900][300] fp32 -> [900][304] f16 (zero-padded) ----------------
__global__ __launch_bounds__(256) void conv_gru_w(const float* __restrict__ gp_whh,
                                                  const float* __restrict__ gc_wih,
                                                  const float* __restrict__ gc_whh,
                                                  _Float16* __restrict__ outp)
{
    int z = blockIdx.y; int l = z/3, wsel = z%3;
    const float* src = (wsel==0?gp_whh:wsel==1?gc_wih:gc_whh) + (size_t)l*G3*DD;
    _Float16* dst = outp + (size_t)z*G3*KP300;
    int idx = blockIdx.x*256 + threadIdx.x;
    if (idx >= G3*KP300) return;
    int n = idx/KP300, k = idx%KP300;
    dst[idx] = (k<DD) ? (_Float16)src[(size_t)n*DD+k] : (_Float16)0.f;
}

// ---------------- transpose-convert [K][N] fp32 -> [N][Kpad] f16 ----------------
__global__ __launch_bounds__(256) void convT(const float* __restrict__ src,
                                             _Float16* __restrict__ dst,
                                             int K, int N, int Kpad)
{
    int idx = blockIdx.x*256 + threadIdx.x;
    if (idx >= N*Kpad) return;
    int n = idx/Kpad, k = idx%Kpad;
    dst[idx] = (k<K) ? (_Float16)src[(size_t)k*N + n] : (_Float16)0.f;
}

// ---------------- MFMA f16 GEMM tile body (device fn, 256 active threads) ----------------
__device__ __forceinline__ void gemm_tile(
    int m0, int n0, int tid,
    const float* __restrict__ A, int lda,
    const _Float16* __restrict__ B, int Kpad,
    const float* __restrict__ bias,
    float* __restrict__ C, int ldc,
    int N, int K, int relu,
    _Float16 (*As)[40], _Float16 (*Bs)[40])
{
    int w = tid>>6, lane = tid&63;
    int wy = w>>1, wx = w&1;
    int lm = lane&15, q = lane>>4;

    f4 acc[4][2];
    #pragma unroll
    for (int a=0;a<4;a++)
        #pragma unroll
        for (int b=0;b<2;b++)
            #pragma unroll
            for (int r=0;r<4;r++) acc[a][b][r]=0.f;

    int am = tid>>1, akg = (tid&1)*16;
    int bn = tid>>2, bkg = (tid&3)*8;
    const float* arow = A + (size_t)(m0+am)*lda;

    for (int k0=0; k0<K; k0+=32){
        {
            __align__(16) _Float16 av[16];
            #pragma unroll
            for (int u=0;u<16;u+=4){
                int k = k0 + akg + u;
                float x0,x1,x2,x3;
                if (k+4 <= K){
                    float4 v = *(const float4*)(arow + k);
                    x0=v.x;x1=v.y;x2=v.z;x3=v.w;
                } else {
                    x0 = (k  <K)? arow[k  ]:0.f;
                    x1 = (k+1<K)? arow[k+1]:0.f;
                    x2 = (k+2<K)? arow[k+2]:0.f;
                    x3 = (k+3<K)? arow[k+3]:0.f;
                }
                av[u]=(_Float16)x0; av[u+1]=(_Float16)x1;
                av[u+2]=(_Float16)x2; av[u+3]=(_Float16)x3;
            }
            *(h8*)&As[am][akg]   = *(h8*)&av[0];
            *(h8*)&As[am][akg+8] = *(h8*)&av[8];
        }
        {
            int gk = k0 + bkg;
            h8 bv;
            #pragma unroll
            for (int j=0;j<8;j++) bv[j]=(_Float16)0.f;
            if (n0+bn < N && gk < Kpad)
                bv = *(const h8*)(B + (size_t)(n0+bn)*Kpad + gk);
            *(h8*)&Bs[bn][bkg] = bv;
        }
        __syncthreads();
        h8 af[4], bf[2];
        #pragma unroll
        for (int mb=0; mb<4; mb++) af[mb] = *(h8*)&As[wy*64+mb*16+lm][q*8];
        #pragma unroll
        for (int nb=0; nb<2; nb++) bf[nb] = *(h8*)&Bs[wx*32+nb*16+lm][q*8];
        #pragma unroll
        for (int mb=0; mb<4; mb++)
            #pragma unroll
            for (int nb=0; nb<2; nb++)
                acc[mb][nb] = __builtin_amdgcn_mfma_f32_16x16x32_f16(af[mb], bf[nb], acc[mb][nb], 0,0,0);
        __syncthreads();
    }
    #pragma unroll
    for (int mb=0; mb<4; mb++){
        int r0 = m0 + wy*64 + mb*16 + q*4;
        #pragma unroll
        for (int nb=0; nb<2; nb++){
            int c = n0 + wx*32 + nb*16 + lm;
            if (c < N){
                float bb = bias[c];
                #pragma unroll
                for (int reg=0; reg<4; reg++){
                    float v = acc[mb][nb][reg] + bb;
                    if (relu) v = fmaxf(v, 0.f);
                    C[(size_t)(r0+reg)*ldc + c] = v;
                }
            }
        }
    }
}

// ---------------- standalone MFMA GEMM kernel ----------------
__global__ __launch_bounds__(256) void gemm_mfma(
    const float* __restrict__ A, int lda,
    const _Float16* __restrict__ B, int Kpad,
    const float* __restrict__ bias,
    float* __restrict__ C, int ldc,
    int N, int K, int relu)
{
    __shared__ _Float16 As[128][40];
    __shared__ _Float16 Bs[64][40];
    gemm_tile(blockIdx.y*128, blockIdx.x*64, threadIdx.x,
              A, lda, B, Kpad, bias, C, ldc, N, K, relu, As, Bs);
}

// ---------------- copy features into last 1024 cols of Hbuf ----------------
__global__ void featcopy(const float* __restrict__ f, float* __restrict__ H)
{
    size_t row = blockIdx.x;
    int t = threadIdx.x;
    float4 v = *(const float4*)(f + row*EE + t*4);
    *(float4*)(H + row*HDIM + 2700 + t*4) = v;
}

// ---------------- fused scan + GIc GEMM ----------------
// blocks 0..47: sequential p-scan. blocks 48..587: GIc GEMM tiles.
// vs R3: (1) q-dot and row-max DELETED via softmax invariance: alpha = q+pk_j+gb
//   and q,gb are j-constant -> cancel; running max m_run (scalar reg) replaces
//   the 6-step max-reduce. pk partial sums move to phase E (pksum[3]).
// (2) phase-C j-loop unrolled 4 (grouped LDS loads).
// (3) 6 weight chunks in LDS (159 KB pool), 32 streamed with unroll 8.
__global__ __launch_bounds__(1024, 4) void scan_kernel(
    float* __restrict__ Hbuf,
    const float* __restrict__ GHp,
    const h8* __restrict__ pwiQ,          // (38,900) h8 chunks of pwi
    const h8* __restrict__ pwhQ,          // (38,900) h8 chunks of pwh (init)
    const float* __restrict__ pbi,
    const float* __restrict__ pbh,
    const float* __restrict__ wk,
    const float* __restrict__ wq,
    const float* __restrict__ gat_b, int lidx,
    const float* __restrict__ adj,
    float* __restrict__ Mbuf,
    int ccol, int hcol, int pcol,
    const _Float16* __restrict__ cwiF,
    const float* __restrict__ cbi,
    float* __restrict__ GIc)
{
    __shared__ __align__(16) char pool[158976];
    (void)wq; (void)gat_b; (void)lidx;   // q and gat_b cancel in softmax

    // ---- GEMM blocks (LDS pool reused as As/Bs) ----
    if (blockIdx.x >= BB){
        if (threadIdx.x < 256){
            _Float16 (*As)[40] = (_Float16 (*)[40])pool;
            _Float16 (*Bs)[40] = (_Float16 (*)[40])(pool + 128*40*2);
            int bid = blockIdx.x - BB;
            int n0 = (bid % 15)*64, m0 = (bid / 15)*128;
            gemm_tile(m0, n0, threadIdx.x, Hbuf + ccol, HDIM, cwiF, KP300,
                      cbi, GIc, G3, G3, DD, 0, As, Bs);
        }
        return;
    }

    int b = blockIdx.x;
    int t = threadIdx.x;

    // ---- LDS pool carve-up (16B aligned) ----
    half2_t (*P_h2)[PP]   = (half2_t (*)[PP])(pool);             //      0: 57600
    h8*      Wlds         = (h8*)(pool + 57600);                 //  57600: 86400 (6 chunks)
    float*   g_s          = (float*)(pool + 144000);             // 144000:  3600
    float  (*Mpart)[DD]   = (float (*)[DD])(pool + 147600);      // 147600:  3600
    float*   ghp_s        = (float*)(pool + 151200);             // 151200:  3600
    float*   hv_s         = (float*)(pool + 154800);             // 154800:  1200
    half2_t* M_h2         = (half2_t*)(pool + 156000);           // 156000:   640
    float*   e_s          = (float*)(pool + 156640);             // 156640:   384
    float*   pk_s         = (float*)(pool + 157024);             // 157024:   384
    float*   pksum        = (float*)(pool + 157408);             // 157408:    32
    unsigned (*adjb)[4]   = (unsigned (*)[4])(pool + 157440);    // 157440:  1536 -> 158976

    size_t rowbase = (size_t)b*NN;

    float pbi_r = (t < G3) ? pbi[t] : 0.f;
    float2 wk_r = make_float2(0.f,0.f);
    if (t < PP) wk_r = *(const float2*)&wk[2*t];

    // ---- init phase 1: LDS weight chunks (0..5) + adj bitmask + Cin0 -> M
    for (int idx=t; idx<NLDS*G3; idx+=1024)
        Wlds[idx] = pwiQ[idx];
    if (t < NN*3){
        int r = t/3, w = t%3;
        const float* arow = adj + (rowbase + r)*NN + w*32;
        unsigned m = 0;
        for (int c=0;c<32;c++) if (arow[c] != 0.f) m |= (1u<<c);
        adjb[r][w] = m;
    }
    if (t < PP){
        float2 c2 = *(const float2*)&Hbuf[rowbase*HDIM + ccol + 2*t];
        Mpart[0][2*t] = c2.x; Mpart[0][2*t+1] = c2.y;
        half2_t mh; mh.x = (_Float16)c2.x; mh.y = (_Float16)c2.y;
        M_h2[t] = mh;
    } else if (t < PP2){
        half2_t z; z.x=(_Float16)0.f; z.y=(_Float16)0.f;
        M_h2[t] = z;
    }
    __syncthreads();
    // ---- init phase 2: gh0 = Cin0 @ pwh^T + pbh
    if (t < G3){
        const h8* W2 = pwhQ + t;
        float a0=0.f, a1=0.f, a2=0.f, a3=0.f;
        #pragma unroll 4
        for (int c=0;c<NC4;c++){
            h8 wv = W2[(size_t)c*G3];
            h8 mc = *(h8*)&M_h2[4*c];
            dot4(wv, mc, a0,a1,a2,a3);
        }
        g_s[t] = pbh[t] + (a0+a2) + (a1+a3);
    }
    __syncthreads();
    // ---- init phase 3: p0 = GRU(x=0, h=Cin0); pk partials; M[b,0]=0
    if (t < 192){
        float pw = 0.f;
        if (t < PP){
            int d0 = 2*t, d1 = 2*t+1;
            float r0  = sigm(pbi[d0]      + g_s[d0]);
            float z0  = sigm(pbi[DD+d0]   + g_s[DD+d0]);
            float n0  = ftanh(pbi[2*DD+d0] + r0*g_s[2*DD+d0]);
            float p0  = (1.f-z0)*n0 + z0*Mpart[0][d0];
            float r1  = sigm(pbi[d1]      + g_s[d1]);
            float z1  = sigm(pbi[DD+d1]   + g_s[DD+d1]);
            float n1  = ftanh(pbi[2*DD+d1] + r1*g_s[2*DD+d1]);
            float p1  = (1.f-z1)*n1 + z1*Mpart[0][d1];
            *(float2*)&Hbuf[rowbase*HDIM + pcol + d0] = make_float2(p0,p1);
            half2_t ph; ph.x = (_Float16)p0; ph.y = (_Float16)p1;
            P_h2[0][t] = ph;
            pw = p0*wk_r.x + p1*wk_r.y;
            *(float2*)&Mbuf[rowbase*DD + d0] = make_float2(0.f,0.f);
        }
        #pragma unroll
        for (int o=32;o>0;o>>=1) pw += __shfl_xor(pw,o);
        if ((t&63)==0) pksum[t>>6] = pw;
    }
    __syncthreads();

    float m_run = NEGI;   // running max of pk (uniform in wave 0)

    for (int i=1;i<NN;i++){
        size_t row = rowbase + i;
        // ---- AB (wave 0): softmax over pk (q,gb cancel; running max m_run)
        if (t < 64){
            float s_last = pksum[0]+pksum[1]+pksum[2];
            if (t==0) pk_s[i-1] = s_last;
            m_run = fmaxf(m_run, s_last);
            float a0 = NEGI, a1 = NEGI;
            if (t < i){
                if ((adjb[i][t>>5]>>(t&31))&1u) a0 = (t==i-1)? s_last : pk_s[t];
            }
            int j1 = 64+t;
            if (t < 32 && j1 < i){
                if ((adjb[i][2]>>t)&1u) a1 = (j1==i-1)? s_last : pk_s[j1];
            }
            float e0 = __expf(a0 - m_run);
            float e1 = (t<32)? __expf(a1 - m_run) : 0.f;
            float ss = e0+e1;
            #pragma unroll
            for (int o=32;o>0;o>>=1) ss += __shfl_xor(ss,o);
            float inv = __fdividef(1.f, ss);
            e_s[t] = e0*inv;
            if (t<32) e_s[64+t] = e1*inv;
        }
        __syncthreads();
        // ---- C (t<450): 3-way j-split weighted sum (unroll 4); prefetchers (t>=512)
        if (t < 450){
            int g = t/150, dp = t%150;
            int cnt = (i+2)/3;
            int j0 = g*cnt; int j1 = j0+cnt; if (j1 > i) j1 = i;
            float m0=0.f, m1=0.f;
            #pragma unroll 4
            for (int j=j0;j<j1;j++){
                float w = e_s[j];
                half2_t pv = P_h2[j][dp];
                m0 += w*(float)pv.x;
                m1 += w*(float)pv.y;
            }
            *(float2*)&Mpart[g][2*dp] = make_float2(m0,m1);
        } else if (t >= 512){
            int k = t-512;
            #pragma unroll
            for (int it=0; it<2; it++){
                int idx = k + it*512;
                if (idx < 450){
                    *(float2*)&ghp_s[2*idx] = *(const float2*)&GHp[row*G3 + 2*idx];
                } else if (idx < 600){
                    int h = idx-450;
                    *(float2*)&hv_s[2*h] = *(const float2*)&Hbuf[row*HDIM + hcol + 2*h];
                }
            }
        }
        __syncthreads();
        // ---- Csum (t<150): combine partials, write Mbuf + f16 M
        if (t < PP){
            float m0 = Mpart[0][2*t] + Mpart[1][2*t] + Mpart[2][2*t];
            float m1 = Mpart[0][2*t+1] + Mpart[1][2*t+1] + Mpart[2][2*t+1];
            half2_t mh; mh.x = (_Float16)m0; mh.y = (_Float16)m1;
            M_h2[t] = mh;
            *(float2*)&Mbuf[row*DD + 2*t] = make_float2(m0,m1);
        }
        __syncthreads();
        // ---- D (t<900): g = M @ pwi^T + pbi; 6 LDS + 32 streamed (unroll 8)
        if (t < G3){
            const h8* W = pwiQ + t;
            const h8* Mc = (const h8*)M_h2;
            float a0=0.f, a1=0.f, a2=0.f, a3=0.f;
            dot4(Wlds[t],        Mc[0], a0,a1,a2,a3);
            dot4(Wlds[G3+t],     Mc[1], a0,a1,a2,a3);
            dot4(Wlds[2*G3+t],   Mc[2], a0,a1,a2,a3);
            dot4(Wlds[3*G3+t],   Mc[3], a0,a1,a2,a3);
            dot4(Wlds[4*G3+t],   Mc[4], a0,a1,a2,a3);
            dot4(Wlds[5*G3+t],   Mc[5], a0,a1,a2,a3);
            #pragma unroll 8
            for (int c=NLDS;c<NC4;c++){
                h8 wv = W[(size_t)c*G3];
                dot4(wv, Mc[c], a0,a1,a2,a3);
            }
            g_s[t] = pbi_r + (a0+a2) + (a1+a3);
        }
        __syncthreads();
        // ---- E (t<192): GRU + pk partials; prefetch unaffected
        if (t < 192){
            float pw = 0.f;
            if (t < PP){
                int d0 = 2*t, d1 = 2*t+1;
                float2 hv = *(const float2*)&hv_s[d0];
                float r0  = sigm(g_s[d0]      + ghp_s[d0]);
                float z0  = sigm(g_s[DD+d0]   + ghp_s[DD+d0]);
                float n0  = ftanh(g_s[2*DD+d0] + r0*ghp_s[2*DD+d0]);
                float p0  = (1.f-z0)*n0 + z0*hv.x;
                float r1  = sigm(g_s[d1]      + ghp_s[d1]);
                float z1  = sigm(g_s[DD+d1]   + ghp_s[DD+d1]);
                float n1  = ftanh(g_s[2*DD+d1] + r1*ghp_s[2*DD+d1]);
                float p1  = (1.f-z1)*n1 + z1*hv.y;
                *(float2*)&Hbuf[row*HDIM + pcol + d0] = make_float2(p0,p1);
                half2_t ph; ph.x = (_Float16)p0; ph.y = (_Float16)p1;
                P_h2[i][t] = ph;
                pw = p0*wk_r.x + p1*wk_r.y;
            }
            #pragma unroll
            for (int o=32;o>0;o>>=1) pw += __shfl_xor(pw,o);
            if ((t&63)==0) pksum[t>>6] = pw;
        }
        __syncthreads();
    }
}

// ---------------- c-side elementwise combine ----------------
__global__ __launch_bounds__(320) void combine_c(
    const float* __restrict__ GIc, const float* __restrict__ GHc,
    const float* __restrict__ Mbuf, float* __restrict__ Hbuf, int clcol)
{
    size_t row = blockIdx.x;
    int d = threadIdx.x;
    if (d < DD){
        float ir = GIc[row*G3+d], iz = GIc[row*G3+DD+d], inn = GIc[row*G3+2*DD+d];
        float hr = GHc[row*G3+d], hz = GHc[row*G3+DD+d], hn  = GHc[row*G3+2*DD+d];
        float r  = sigm(ir+hr);
        float z  = sigm(iz+hz);
        float nn = ftanh(inn + r*hn);
        float h  = Mbuf[row*DD+d];
        Hbuf[row*HDIM + clcol + d] = (1.f-z)*nn + z*h;
    }
}

// ---------------- logits: out = x2 @ w2 + b2 (N=7) ----------------
__global__ __launch_bounds__(64) void logits_kernel(
    const float* __restrict__ x2, const float* __restrict__ w2,
    const float* __restrict__ b2, float* __restrict__ out)
{
    size_t row = blockIdx.x;
    int lane = threadIdx.x;
    float acc[7]={0,0,0,0,0,0,0};
    for (int d=lane; d<DD; d+=64){
        float x = x2[row*DD+d];
        #pragma unroll
        for (int c=0;c<7;c++) acc[c] += x*w2[d*7+c];
    }
    #pragma unroll
    for (int c=0;c<7;c++){
        float s = acc[c];
        #pragma unroll
        for (int o=32;o>0;o>>=1) s += __shfl_down(s,o);
        if (lane==0) out[row*7+c] = s + b2[c];
    }
}

extern "C" void kernel_launch(void* const* d_in, const int* in_sizes, int n_in,
                              void* d_out, int out_size, void* d_ws, size_t ws_size,
                              hipStream_t stream)
{
    const float* features = (const float*)d_in[0];
    const float* adj      = (const float*)d_in[1];
    const float* fc1_w    = (const float*)d_in[3];
    const float* fc1_b    = (const float*)d_in[4];
    const float* gc_wih   = (const float*)d_in[5];
    const float* gc_whh   = (const float*)d_in[6];
    const float* gc_bih   = (const float*)d_in[7];
    const float* gc_bhh   = (const float*)d_in[8];
    const float* gp_wih   = (const float*)d_in[9];
    const float* gp_whh   = (const float*)d_in[10];
    const float* gp_bih   = (const float*)d_in[11];
    const float* gp_bhh   = (const float*)d_in[12];
    const float* gat_wq   = (const float*)d_in[13];
    const float* gat_wk   = (const float*)d_in[14];
    const float* gat_b    = (const float*)d_in[15];
    const float* mlp_w0   = (const float*)d_in[16];
    const float* mlp_b0   = (const float*)d_in[17];
    const float* mlp_w1   = (const float*)d_in[18];
    const float* mlp_b1   = (const float*)d_in[19];
    const float* mlp_w2   = (const float*)d_in[20];
    const float* mlp_b2   = (const float*)d_in[21];
    float* out = (float*)d_out;

    float* ws = (float*)d_ws;
    size_t off = 0;
    float* Hbuf = ws + off; off += (size_t)ROWS*HDIM;
    float* bufA = ws + off; off += (size_t)ROWS*G3;    // GHp
    float* bufB = ws + off; off += (size_t)ROWS*G3;    // GIc / x1
    float* bufC = ws + off; off += (size_t)ROWS*G3;    // GHc / x2
    float* Mbuf = ws + off; off += (size_t)ROWS*DD;
    h8* pwiQ = (h8*)(ws + off); off += (size_t)LL*NC4*G3*4;
    h8* pwhQ = (h8*)(ws + off); off += (size_t)LL*NC4*G3*4;
    _Float16* gruF = (_Float16*)(ws + off); off += (size_t)12*G3*KP300/2;
    _Float16* fc1F = (_Float16*)(ws + off); off += (size_t)DD*EE/2;
    _Float16* mlp0F= (_Float16*)(ws + off); off += (size_t)DD*3728/2;
    _Float16* mlp1F= (_Float16*)(ws + off); off += (size_t)DD*KP300/2;
    (void)ws_size; (void)in_sizes; (void)n_in; (void)out_size;

    // 1. weight prep
    {
        pack_w_q<<<dim3((NC4*G3+255)/256, LL), 256, 0, stream>>>(gp_wih, pwiQ);
        pack_w_q<<<dim3((NC4*G3+255)/256, LL), 256, 0, stream>>>(gp_whh, pwhQ);
        conv_gru_w<<<dim3((G3*KP300+255)/256, 12), 256, 0, stream>>>(gp_whh, gc_wih, gc_whh, gruF);
        convT<<<(DD*EE+255)/256, 256, 0, stream>>>(fc1_w, fc1F, EE, DD, EE);
        convT<<<(DD*3728+255)/256, 256, 0, stream>>>(mlp_w0, mlp0F, HDIM, DD, 3728);
        convT<<<(DD*KP300+255)/256, 256, 0, stream>>>(mlp_w1, mlp1F, DD, DD, KP300);
    }
    // 2. H0 = relu(features @ fc1_w + fc1_b) -> Hbuf col 0
    gemm_mfma<<<dim3(5,36),256,0,stream>>>(features, EE, fc1F, EE, fc1_b,
                                           Hbuf, HDIM, DD, EE, 1);
    // 3. features -> Hbuf cols [2700,3724)
    featcopy<<<ROWS,256,0,stream>>>(features, Hbuf);

    for (int l=0;l<LL;l++){
        int ccol  = (l==0)? 0 : 300 + (l-1)*600;
        int hcol  = l*300;
        int pcol  = 600 + l*600;
        int clcol = 300 + l*600;
        const h8* pwiQl = pwiQ + (size_t)l*NC4*G3;
        const h8* pwhQl = pwhQ + (size_t)l*NC4*G3;
        const _Float16* pwhF = gruF + (size_t)(l*3+0)*G3*KP300;
        const _Float16* cwiF = gruF + (size_t)(l*3+1)*G3*KP300;
        const _Float16* cwhF = gruF + (size_t)(l*3+2)*G3*KP300;

        // GHp = Hin @ pwh^T + pbh
        gemm_mfma<<<dim3(15,36),256,0,stream>>>(Hbuf+hcol, HDIM, pwhF, KP300,
                                                gp_bhh + l*G3, bufA, G3, G3, DD, 0);
        // fused: scan (blocks 0..47) + GIc GEMM (blocks 48..587)
        scan_kernel<<<BB+GIC_TILES,1024,0,stream>>>(Hbuf, bufA, pwiQl, pwhQl,
                                          gp_bih + l*G3, gp_bhh + l*G3,
                                          gat_wk + l*DD, gat_wq + l*DD, gat_b, l,
                                          adj, Mbuf, ccol, hcol, pcol,
                                          cwiF, gc_bih + l*G3, bufB);
        // GHc = M @ cwh^T + cbh
        gemm_mfma<<<dim3(15,36),256,0,stream>>>(Mbuf, DD, cwhF, KP300,
                                                gc_bhh + l*G3, bufC, G3, G3, DD, 0);
        // CL = GRU-combine
        combine_c<<<ROWS,320,0,stream>>>(bufB, bufC, Mbuf, Hbuf, clcol);
    }

    // MLP
    gemm_mfma<<<dim3(5,36),256,0,stream>>>(Hbuf, HDIM, mlp0F, 3728, mlp_b0,
                                           bufB, DD, DD, HDIM, 1);
    gemm_mfma<<<dim3(5,36),256,0,stream>>>(bufB, DD, mlp1F, KP300, mlp_b1,
                                           bufC, DD, DD, DD, 1);
    logits_kernel<<<ROWS,64,0,stream>>>(bufC, mlp_w2, mlp_b2, out);
}

// Round 6
// 2676.370 us; speedup vs baseline: 1.2187x; 1.1271x over previous
//
#include <hip/hip_runtime.h>
#include <math.h>

#define BB 48
#define NN 96
#define EE 1024
#define DD 300
#define LL 4
#define G3 900          // 3*D
#define PP 150          // DD/2 f16 pairs
#define PP2 152         // padded pairs (38 chunks of 4)
#define NC4 38          // weight chunks of 4 pairs
#define HDIM 3724       // D*(2L+1)+E
#define ROWS (BB*NN)    // 4608
#define NEGI -1.0e30f
#define KP300 304       // 300 padded to mult-of-8
#define GIC_TILES 540   // 15 x 36 tiles for fused GIc GEMM

#define NLDS 6          // pwi chunks resident in LDS (86400 B), ids 0..5
#define NPIN 14         // pwi chunks pinned in VGPRs (56 regs), ids 6..19
// streamed chunks in phase D: 20..37 (18 chunks)

typedef _Float16 half2_t __attribute__((ext_vector_type(2)));
typedef _Float16 h8 __attribute__((ext_vector_type(8)));
typedef float f4 __attribute__((ext_vector_type(4)));

__device__ __forceinline__ float sigm(float x){
    return __fdividef(1.0f, 1.0f + __expf(-x));
}
__device__ __forceinline__ float ftanh(float x){
    float e = __expf(2.0f*x);
    return 1.0f - __fdividef(2.0f, e + 1.0f);
}

__device__ __forceinline__ void dot4(const h8 wv, const h8 mc,
                                     float& a0, float& a1, float& a2, float& a3)
{
    half2_t w0,w1,w2,w3,m0,m1,m2,m3;
    w0.x=wv[0]; w0.y=wv[1]; m0.x=mc[0]; m0.y=mc[1];
    w1.x=wv[2]; w1.y=wv[3]; m1.x=mc[2]; m1.y=mc[3];
    w2.x=wv[4]; w2.y=wv[5]; m2.x=mc[4]; m2.y=mc[5];
    w3.x=wv[6]; w3.y=wv[7]; m3.x=mc[6]; m3.y=mc[7];
    a0 = __builtin_amdgcn_fdot2(w0, m0, a0, false);
    a1 = __builtin_amdgcn_fdot2(w1, m1, a1, false);
    a2 = __builtin_amdgcn_fdot2(w2, m2, a2, false);
    a3 = __builtin_amdgcn_fdot2(w3, m3, a3, false);
}

// ---------------- pack W (L,900,300) -> coalesced h8 chunks (L,38,900) ----------------
__global__ __launch_bounds__(256) void pack_w_q(const float* __restrict__ src_all,
                                                h8* __restrict__ dst)
{
    int l = blockIdx.y;
    int idx = blockIdx.x*256 + threadIdx.x;
    if (idx >= NC4*G3) return;
    int c = idx / G3, gate = idx % G3;
    const float* src = src_all + (size_t)l*G3*DD + (size_t)gate*DD;
    h8 v;
    #pragma unroll
    for (int j=0;j<8;j++){
        int d = 8*c + j;
        v[j] = (d<DD) ? (_Float16)src[d] : (_Float16)0.f;
    }
    dst[(size_t)l*NC4*G3 + idx] = v;
}

// ---------------- GRU weights [900][300] fp32 -> [900][304] f16 (zero-padded) ----------------
__global__ __launch_bounds__(256) void conv_gru_w(const float* __restrict__ gp_whh,
                                                  const float* __restrict__ gc_wih,
                                                  const float* __restrict__ gc_whh,
                                                  _Float16* __restrict__ outp)
{
    int z = blockIdx.y; int l = z/3, wsel = z%3;
    const float* src = (wsel==0?gp_whh:wsel==1?gc_wih:gc_whh) + (size_t)l*G3*DD;
    _Float16* dst = outp + (size_t)z*G3*KP300;
    int idx = blockIdx.x*256 + threadIdx.x;
    if (idx >= G3*KP300) return;
    int n = idx/KP300, k = idx%KP300;
    dst[idx] = (k<DD) ? (_Float16)src[(size_t)n*DD+k] : (_Float16)0.f;
}

// ---------------- transpose-convert [K][N] fp32 -> [N][Kpad] f16 ----------------
__global__ __launch_bounds__(256) void convT(const float* __restrict__ src,
                                             _Float16* __restrict__ dst,
                                             int K, int N, int Kpad)
{
    int idx = blockIdx.x*256 + threadIdx.x;
    if (idx >= N*Kpad) return;
    int n = idx/Kpad, k = idx%Kpad;
    dst[idx] = (k<K) ? (_Float16)src[(size_t)k*N + n] : (_Float16)0.f;
}

// ---------------- MFMA f16 GEMM tile body (device fn, 256 active threads) ----------------
__device__ __forceinline__ void gemm_tile(
    int m0, int n0, int tid,
    const float* __restrict__ A, int lda,
    const _Float16* __restrict__ B, int Kpad,
    const float* __restrict__ bias,
    float* __restrict__ C, int ldc,
    int N, int K, int relu,
    _Float16 (*As)[40], _Float16 (*Bs)[40])
{
    int w = tid>>6, lane = tid&63;
    int wy = w>>1, wx = w&1;
    int lm = lane&15, q = lane>>4;

    f4 acc[4][2];
    #pragma unroll
    for (int a=0;a<4;a++)
        #pragma unroll
        for (int b=0;b<2;b++)
            #pragma unroll
            for (int r=0;r<4;r++) acc[a][b][r]=0.f;

    int am = tid>>1, akg = (tid&1)*16;
    int bn = tid>>2, bkg = (tid&3)*8;
    const float* arow = A + (size_t)(m0+am)*lda;

    for (int k0=0; k0<K; k0+=32){
        {
            __align__(16) _Float16 av[16];
            #pragma unroll
            for (int u=0;u<16;u+=4){
                int k = k0 + akg + u;
                float x0,x1,x2,x3;
                if (k+4 <= K){
                    float4 v = *(const float4*)(arow + k);
                    x0=v.x;x1=v.y;x2=v.z;x3=v.w;
                } else {
                    x0 = (k  <K)? arow[k  ]:0.f;
                    x1 = (k+1<K)? arow[k+1]:0.f;
                    x2 = (k+2<K)? arow[k+2]:0.f;
                    x3 = (k+3<K)? arow[k+3]:0.f;
                }
                av[u]=(_Float16)x0; av[u+1]=(_Float16)x1;
                av[u+2]=(_Float16)x2; av[u+3]=(_Float16)x3;
            }
            *(h8*)&As[am][akg]   = *(h8*)&av[0];
            *(h8*)&As[am][akg+8] = *(h8*)&av[8];
        }
        {
            int gk = k0 + bkg;
            h8 bv;
            #pragma unroll
            for (int j=0;j<8;j++) bv[j]=(_Float16)0.f;
            if (n0+bn < N && gk < Kpad)
                bv = *(const h8*)(B + (size_t)(n0+bn)*Kpad + gk);
            *(h8*)&Bs[bn][bkg] = bv;
        }
        __syncthreads();
        h8 af[4], bf[2];
        #pragma unroll
        for (int mb=0; mb<4; mb++) af[mb] = *(h8*)&As[wy*64+mb*16+lm][q*8];
        #pragma unroll
        for (int nb=0; nb<2; nb++) bf[nb] = *(h8*)&Bs[wx*32+nb*16+lm][q*8];
        #pragma unroll
        for (int mb=0; mb<4; mb++)
            #pragma unroll
            for (int nb=0; nb<2; nb++)
                acc[mb][nb] = __builtin_amdgcn_mfma_f32_16x16x32_f16(af[mb], bf[nb], acc[mb][nb], 0,0,0);
        __syncthreads();
    }
    #pragma unroll
    for (int mb=0; mb<4; mb++){
        int r0 = m0 + wy*64 + mb*16 + q*4;
        #pragma unroll
        for (int nb=0; nb<2; nb++){
            int c = n0 + wx*32 + nb*16 + lm;
            if (c < N){
                float bb = bias[c];
                #pragma unroll
                for (int reg=0; reg<4; reg++){
                    float v = acc[mb][nb][reg] + bb;
                    if (relu) v = fmaxf(v, 0.f);
                    C[(size_t)(r0+reg)*ldc + c] = v;
                }
            }
        }
    }
}

// ---------------- standalone MFMA GEMM kernel ----------------
__global__ __launch_bounds__(256) void gemm_mfma(
    const float* __restrict__ A, int lda,
    const _Float16* __restrict__ B, int Kpad,
    const float* __restrict__ bias,
    float* __restrict__ C, int ldc,
    int N, int K, int relu)
{
    __shared__ _Float16 As[128][40];
    __shared__ _Float16 Bs[64][40];
    gemm_tile(blockIdx.y*128, blockIdx.x*64, threadIdx.x,
              A, lda, B, Kpad, bias, C, ldc, N, K, relu, As, Bs);
}

// ---------------- copy features into last 1024 cols of Hbuf ----------------
__global__ void featcopy(const float* __restrict__ f, float* __restrict__ H)
{
    size_t row = blockIdx.x;
    int t = threadIdx.x;
    float4 v = *(const float4*)(f + row*EE + t*4);
    *(float4*)(H + row*HDIM + 2700 + t*4) = v;
}

// ---------------- fused scan + GIc GEMM ----------------
// blocks 0..47: sequential p-scan. blocks 48..587: GIc GEMM tiles.
// vs R5: amdgpu_waves_per_eu(4,4) caps occupancy at 1 block/CU (which the
// 159KB LDS already forces) so the allocator's register budget is 128/thread
// instead of the 64-reg bin it was spilling to hit. With that headroom, 14
// weight chunks (56 VGPRs) are loaded ONCE before the loop (asm anti-remat
// anchor) and stay resident. Phase D: 6 LDS + 14 reg + 18 streamed
// (260KB/step through L1 vs R5's 460KB).
__global__ void __launch_bounds__(1024)
__attribute__((amdgpu_waves_per_eu(4,4)))
scan_kernel(
    float* __restrict__ Hbuf,
    const float* __restrict__ GHp,
    const h8* __restrict__ pwiQ,          // (38,900) h8 chunks of pwi
    const h8* __restrict__ pwhQ,          // (38,900) h8 chunks of pwh (init)
    const float* __restrict__ pbi,
    const float* __restrict__ pbh,
    const float* __restrict__ wk,
    const float* __restrict__ wq,
    const float* __restrict__ gat_b, int lidx,
    const float* __restrict__ adj,
    float* __restrict__ Mbuf,
    int ccol, int hcol, int pcol,
    const _Float16* __restrict__ cwiF,
    const float* __restrict__ cbi,
    float* __restrict__ GIc)
{
    __shared__ __align__(16) char pool[158976];
    (void)wq; (void)gat_b; (void)lidx;   // q and gat_b cancel in softmax

    // ---- GEMM blocks (LDS pool reused as As/Bs) ----
    if (blockIdx.x >= BB){
        if (threadIdx.x < 256){
            _Float16 (*As)[40] = (_Float16 (*)[40])pool;
            _Float16 (*Bs)[40] = (_Float16 (*)[40])(pool + 128*40*2);
            int bid = blockIdx.x - BB;
            int n0 = (bid % 15)*64, m0 = (bid / 15)*128;
            gemm_tile(m0, n0, threadIdx.x, Hbuf + ccol, HDIM, cwiF, KP300,
                      cbi, GIc, G3, G3, DD, 0, As, Bs);
        }
        return;
    }

    int b = blockIdx.x;
    int t = threadIdx.x;

    // ---- LDS pool carve-up (16B aligned) ----
    half2_t (*P_h2)[PP]   = (half2_t (*)[PP])(pool);             //      0: 57600
    h8*      Wlds         = (h8*)(pool + 57600);                 //  57600: 86400 (6 chunks)
    float*   g_s          = (float*)(pool + 144000);             // 144000:  3600
    float  (*Mpart)[DD]   = (float (*)[DD])(pool + 147600);      // 147600:  3600
    float*   ghp_s        = (float*)(pool + 151200);             // 151200:  3600
    float*   hv_s         = (float*)(pool + 154800);             // 154800:  1200
    half2_t* M_h2         = (half2_t*)(pool + 156000);           // 156000:   640
    float*   e_s          = (float*)(pool + 156640);             // 156640:   384
    float*   pk_s         = (float*)(pool + 157024);             // 157024:   384
    float*   pksum        = (float*)(pool + 157408);             // 157408:    32
    unsigned (*adjb)[4]   = (unsigned (*)[4])(pool + 157440);    // 157440:  1536 -> 158976

    size_t rowbase = (size_t)b*NN;

    float pbi_r = (t < G3) ? pbi[t] : 0.f;
    float2 wk_r = make_float2(0.f,0.f);
    if (t < PP) wk_r = *(const float2*)&wk[2*t];

    // ---- one-time: 14 pinned weight chunks (ids 6..19), anti-remat anchored
    h8 wp0,wp1,wp2,wp3,wp4,wp5,wp6,wp7,wp8,wp9,wp10,wp11,wp12,wp13;
    if (t < G3){
        const h8* W = pwiQ + t;
        wp0 = W[(size_t)6*G3];   wp1 = W[(size_t)7*G3];   wp2 = W[(size_t)8*G3];
        wp3 = W[(size_t)9*G3];   wp4 = W[(size_t)10*G3];  wp5 = W[(size_t)11*G3];
        wp6 = W[(size_t)12*G3];  wp7 = W[(size_t)13*G3];  wp8 = W[(size_t)14*G3];
        wp9 = W[(size_t)15*G3];  wp10 = W[(size_t)16*G3]; wp11 = W[(size_t)17*G3];
        wp12 = W[(size_t)18*G3]; wp13 = W[(size_t)19*G3];
        asm volatile("" : "+v"(wp0),"+v"(wp1),"+v"(wp2),"+v"(wp3),
                          "+v"(wp4),"+v"(wp5),"+v"(wp6));
        asm volatile("" : "+v"(wp7),"+v"(wp8),"+v"(wp9),"+v"(wp10),
                          "+v"(wp11),"+v"(wp12),"+v"(wp13));
    }

    // ---- init phase 1: LDS weight chunks (0..5) + adj bitmask + Cin0 -> M
    for (int idx=t; idx<NLDS*G3; idx+=1024)
        Wlds[idx] = pwiQ[idx];
    if (t < NN*3){
        int r = t/3, w = t%3;
        const float* arow = adj + (rowbase + r)*NN + w*32;
        unsigned m = 0;
        for (int c=0;c<32;c++) if (arow[c] != 0.f) m |= (1u<<c);
        adjb[r][w] = m;
    }
    if (t < PP){
        float2 c2 = *(const float2*)&Hbuf[rowbase*HDIM + ccol + 2*t];
        Mpart[0][2*t] = c2.x; Mpart[0][2*t+1] = c2.y;
        half2_t mh; mh.x = (_Float16)c2.x; mh.y = (_Float16)c2.y;
        M_h2[t] = mh;
    } else if (t < PP2){
        half2_t z; z.x=(_Float16)0.f; z.y=(_Float16)0.f;
        M_h2[t] = z;
    }
    __syncthreads();
    // ---- init phase 2: gh0 = Cin0 @ pwh^T + pbh
    if (t < G3){
        const h8* W2 = pwhQ + t;
        float a0=0.f, a1=0.f, a2=0.f, a3=0.f;
        #pragma unroll 4
        for (int c=0;c<NC4;c++){
            h8 wv = W2[(size_t)c*G3];
            h8 mc = *(h8*)&M_h2[4*c];
            dot4(wv, mc, a0,a1,a2,a3);
        }
        g_s[t] = pbh[t] + (a0+a2) + (a1+a3);
    }
    __syncthreads();
    // ---- init phase 3: p0 = GRU(x=0, h=Cin0); pk partials; M[b,0]=0
    if (t < 192){
        float pw = 0.f;
        if (t < PP){
            int d0 = 2*t, d1 = 2*t+1;
            float r0  = sigm(pbi[d0]      + g_s[d0]);
            float z0  = sigm(pbi[DD+d0]   + g_s[DD+d0]);
            float n0  = ftanh(pbi[2*DD+d0] + r0*g_s[2*DD+d0]);
            float p0  = (1.f-z0)*n0 + z0*Mpart[0][d0];
            float r1  = sigm(pbi[d1]      + g_s[d1]);
            float z1  = sigm(pbi[DD+d1]   + g_s[DD+d1]);
            float n1  = ftanh(pbi[2*DD+d1] + r1*g_s[2*DD+d1]);
            float p1  = (1.f-z1)*n1 + z1*Mpart[0][d1];
            *(float2*)&Hbuf[rowbase*HDIM + pcol + d0] = make_float2(p0,p1);
            half2_t ph; ph.x = (_Float16)p0; ph.y = (_Float16)p1;
            P_h2[0][t] = ph;
            pw = p0*wk_r.x + p1*wk_r.y;
            *(float2*)&Mbuf[rowbase*DD + d0] = make_float2(0.f,0.f);
        }
        #pragma unroll
        for (int o=32;o>0;o>>=1) pw += __shfl_xor(pw,o);
        if ((t&63)==0) pksum[t>>6] = pw;
    }
    __syncthreads();

    float m_run = NEGI;   // running max of pk (uniform in wave 0)

    for (int i=1;i<NN;i++){
        size_t row = rowbase + i;
        // ---- AB (wave 0): softmax over pk (q,gb cancel; running max m_run)
        if (t < 64){
            float s_last = pksum[0]+pksum[1]+pksum[2];
            if (t==0) pk_s[i-1] = s_last;
            m_run = fmaxf(m_run, s_last);
            float a0 = NEGI, a1 = NEGI;
            if (t < i){
                if ((adjb[i][t>>5]>>(t&31))&1u) a0 = (t==i-1)? s_last : pk_s[t];
            }
            int j1 = 64+t;
            if (t < 32 && j1 < i){
                if ((adjb[i][2]>>t)&1u) a1 = (j1==i-1)? s_last : pk_s[j1];
            }
            float e0 = __expf(a0 - m_run);
            float e1 = (t<32)? __expf(a1 - m_run) : 0.f;
            float ss = e0+e1;
            #pragma unroll
            for (int o=32;o>0;o>>=1) ss += __shfl_xor(ss,o);
            float inv = __fdividef(1.f, ss);
            e_s[t] = e0*inv;
            if (t<32) e_s[64+t] = e1*inv;
        }
        __syncthreads();
        // ---- C (t<450): 3-way j-split weighted sum (unroll 4); prefetchers (t>=512)
        if (t < 450){
            int g = t/150, dp = t%150;
            int cnt = (i+2)/3;
            int j0 = g*cnt; int j1 = j0+cnt; if (j1 > i) j1 = i;
            float m0=0.f, m1=0.f;
            #pragma unroll 4
            for (int j=j0;j<j1;j++){
                float w = e_s[j];
                half2_t pv = P_h2[j][dp];
                m0 += w*(float)pv.x;
                m1 += w*(float)pv.y;
            }
            *(float2*)&Mpart[g][2*dp] = make_float2(m0,m1);
        } else if (t >= 512){
            int k = t-512;
            #pragma unroll
            for (int it=0; it<2; it++){
                int idx = k + it*512;
                if (idx < 450){
                    *(float2*)&ghp_s[2*idx] = *(const float2*)&GHp[row*G3 + 2*idx];
                } else if (idx < 600){
                    int h = idx-450;
                    *(float2*)&hv_s[2*h] = *(const float2*)&Hbuf[row*HDIM + hcol + 2*h];
                }
            }
        }
        __syncthreads();
        // ---- Csum (t<150): combine partials, write Mbuf + f16 M
        if (t < PP){
            float m0 = Mpart[0][2*t] + Mpart[1][2*t] + Mpart[2][2*t];
            float m1 = Mpart[0][2*t+1] + Mpart[1][2*t+1] + Mpart[2][2*t+1];
            half2_t mh; mh.x = (_Float16)m0; mh.y = (_Float16)m1;
            M_h2[t] = mh;
            *(float2*)&Mbuf[row*DD + 2*t] = make_float2(m0,m1);
        }
        __syncthreads();
        // ---- D (t<900): g = M @ pwi^T + pbi; 6 LDS + 14 pinned + 18 streamed
        if (t < G3){
            const h8* W = pwiQ + t;
            const h8* Mc = (const h8*)M_h2;
            float a0=0.f, a1=0.f, a2=0.f, a3=0.f;
            dot4(Wlds[t],        Mc[0], a0,a1,a2,a3);
            dot4(Wlds[G3+t],     Mc[1], a0,a1,a2,a3);
            dot4(Wlds[2*G3+t],   Mc[2], a0,a1,a2,a3);
            dot4(Wlds[3*G3+t],   Mc[3], a0,a1,a2,a3);
            dot4(Wlds[4*G3+t],   Mc[4], a0,a1,a2,a3);
            dot4(Wlds[5*G3+t],   Mc[5], a0,a1,a2,a3);
            dot4(wp0,  Mc[6],  a0,a1,a2,a3);
            dot4(wp1,  Mc[7],  a0,a1,a2,a3);
            dot4(wp2,  Mc[8],  a0,a1,a2,a3);
            dot4(wp3,  Mc[9],  a0,a1,a2,a3);
            dot4(wp4,  Mc[10], a0,a1,a2,a3);
            dot4(wp5,  Mc[11], a0,a1,a2,a3);
            dot4(wp6,  Mc[12], a0,a1,a2,a3);
            dot4(wp7,  Mc[13], a0,a1,a2,a3);
            dot4(wp8,  Mc[14], a0,a1,a2,a3);
            dot4(wp9,  Mc[15], a0,a1,a2,a3);
            dot4(wp10, Mc[16], a0,a1,a2,a3);
            dot4(wp11, Mc[17], a0,a1,a2,a3);
            dot4(wp12, Mc[18], a0,a1,a2,a3);
            dot4(wp13, Mc[19], a0,a1,a2,a3);
            #pragma unroll 6
            for (int c=NLDS+NPIN;c<NC4;c++){
                h8 wv = W[(size_t)c*G3];
                dot4(wv, Mc[c], a0,a1,a2,a3);
            }
            g_s[t] = pbi_r + (a0+a2) + (a1+a3);
        }
        __syncthreads();
        // ---- E (t<192): GRU + pk partials; prefetch unaffected
        if (t < 192){
            float pw = 0.f;
            if (t < PP){
                int d0 = 2*t, d1 = 2*t+1;
                float2 hv = *(const float2*)&hv_s[d0];
                float r0  = sigm(g_s[d0]      + ghp_s[d0]);
                float z0  = sigm(g_s[DD+d0]   + ghp_s[DD+d0]);
                float n0  = ftanh(g_s[2*DD+d0] + r0*ghp_s[2*DD+d0]);
                float p0  = (1.f-z0)*n0 + z0*hv.x;
                float r1  = sigm(g_s[d1]      + ghp_s[d1]);
                float z1  = sigm(g_s[DD+d1]   + ghp_s[DD+d1]);
                float n1  = ftanh(g_s[2*DD+d1] + r1*ghp_s[2*DD+d1]);
                float p1  = (1.f-z1)*n1 + z1*hv.y;
                *(float2*)&Hbuf[row*HDIM + pcol + d0] = make_float2(p0,p1);
                half2_t ph; ph.x = (_Float16)p0; ph.y = (_Float16)p1;
                P_h2[i][t] = ph;
                pw = p0*wk_r.x + p1*wk_r.y;
            }
            #pragma unroll
            for (int o=32;o>0;o>>=1) pw += __shfl_xor(pw,o);
            if ((t&63)==0) pksum[t>>6] = pw;
        }
        __syncthreads();
    }
}

// ---------------- c-side elementwise combine ----------------
__global__ __launch_bounds__(320) void combine_c(
    const float* __restrict__ GIc, const float* __restrict__ GHc,
    const float* __restrict__ Mbuf, float* __restrict__ Hbuf, int clcol)
{
    size_t row = blockIdx.x;
    int d = threadIdx.x;
    if (d < DD){
        float ir = GIc[row*G3+d], iz = GIc[row*G3+DD+d], inn = GIc[row*G3+2*DD+d];
        float hr = GHc[row*G3+d], hz = GHc[row*G3+DD+d], hn  = GHc[row*G3+2*DD+d];
        float r  = sigm(ir+hr);
        float z  = sigm(iz+hz);
        float nn = ftanh(inn + r*hn);
        float h  = Mbuf[row*DD+d];
        Hbuf[row*HDIM + clcol + d] = (1.f-z)*nn + z*h;
    }
}

// ---------------- logits: out = x2 @ w2 + b2 (N=7) ----------------
__global__ __launch_bounds__(64) void logits_kernel(
    const float* __restrict__ x2, const float* __restrict__ w2,
    const float* __restrict__ b2, float* __restrict__ out)
{
    size_t row = blockIdx.x;
    int lane = threadIdx.x;
    float acc[7]={0,0,0,0,0,0,0};
    for (int d=lane; d<DD; d+=64){
        float x = x2[row*DD+d];
        #pragma unroll
        for (int c=0;c<7;c++) acc[c] += x*w2[d*7+c];
    }
    #pragma unroll
    for (int c=0;c<7;c++){
        float s = acc[c];
        #pragma unroll
        for (int o=32;o>0;o>>=1) s += __shfl_down(s,o);
        if (lane==0) out[row*7+c] = s + b2[c];
    }
}

extern "C" void kernel_launch(void* const* d_in, const int* in_sizes, int n_in,
                              void* d_out, int out_size, void* d_ws, size_t ws_size,
                              hipStream_t stream)
{
    const float* features = (const float*)d_in[0];
    const float* adj      = (const float*)d_in[1];
    const float* fc1_w    = (const float*)d_in[3];
    const float* fc1_b    = (const float*)d_in[4];
    const float* gc_wih   = (const float*)d_in[5];
    const float* gc_whh   = (const float*)d_in[6];
    const float* gc_bih   = (const float*)d_in[7];
    const float* gc_bhh   = (const float*)d_in[8];
    const float* gp_wih   = (const float*)d_in[9];
    const float* gp_whh   = (const float*)d_in[10];
    const float* gp_bih   = (const float*)d_in[11];
    const float* gp_bhh   = (const float*)d_in[12];
    const float* gat_wq   = (const float*)d_in[13];
    const float* gat_wk   = (const float*)d_in[14];
    const float* gat_b    = (const float*)d_in[15];
    const float* mlp_w0   = (const float*)d_in[16];
    const float* mlp_b0   = (const float*)d_in[17];
    const float* mlp_w1   = (const float*)d_in[18];
    const float* mlp_b1   = (const float*)d_in[19];
    const float* mlp_w2   = (const float*)d_in[20];
    const float* mlp_b2   = (const float*)d_in[21];
    float* out = (float*)d_out;

    float* ws = (float*)d_ws;
    size_t off = 0;
    float* Hbuf = ws + off; off += (size_t)ROWS*HDIM;
    float* bufA = ws + off; off += (size_t)ROWS*G3;    // GHp
    float* bufB = ws + off; off += (size_t)ROWS*G3;    // GIc / x1
    float* bufC = ws + off; off += (size_t)ROWS*G3;    // GHc / x2
    float* Mbuf = ws + off; off += (size_t)ROWS*DD;
    h8* pwiQ = (h8*)(ws + off); off += (size_t)LL*NC4*G3*4;
    h8* pwhQ = (h8*)(ws + off); off += (size_t)LL*NC4*G3*4;
    _Float16* gruF = (_Float16*)(ws + off); off += (size_t)12*G3*KP300/2;
    _Float16* fc1F = (_Float16*)(ws + off); off += (size_t)DD*EE/2;
    _Float16* mlp0F= (_Float16*)(ws + off); off += (size_t)DD*3728/2;
    _Float16* mlp1F= (_Float16*)(ws + off); off += (size_t)DD*KP300/2;
    (void)ws_size; (void)in_sizes; (void)n_in; (void)out_size;

    // 1. weight prep
    {
        pack_w_q<<<dim3((NC4*G3+255)/256, LL), 256, 0, stream>>>(gp_wih, pwiQ);
        pack_w_q<<<dim3((NC4*G3+255)/256, LL), 256, 0, stream>>>(gp_whh, pwhQ);
        conv_gru_w<<<dim3((G3*KP300+255)/256, 12), 256, 0, stream>>>(gp_whh, gc_wih, gc_whh, gruF);
        convT<<<(DD*EE+255)/256, 256, 0, stream>>>(fc1_w, fc1F, EE, DD, EE);
        convT<<<(DD*3728+255)/256, 256, 0, stream>>>(mlp_w0, mlp0F, HDIM, DD, 3728);
        convT<<<(DD*KP300+255)/256, 256, 0, stream>>>(mlp_w1, mlp1F, DD, DD, KP300);
    }
    // 2. H0 = relu(features @ fc1_w + fc1_b) -> Hbuf col 0
    gemm_mfma<<<dim3(5,36),256,0,stream>>>(features, EE, fc1F, EE, fc1_b,
                                           Hbuf, HDIM, DD, EE, 1);
    // 3. features -> Hbuf cols [2700,3724)
    featcopy<<<ROWS,256,0,stream>>>(features, Hbuf);

    for (int l=0;l<LL;l++){
        int ccol  = (l==0)? 0 : 300 + (l-1)*600;
        int hcol  = l*300;
        int pcol  = 600 + l*600;
        int clcol = 300 + l*600;
        const h8* pwiQl = pwiQ + (size_t)l*NC4*G3;
        const h8* pwhQl = pwhQ + (size_t)l*NC4*G3;
        const _Float16* pwhF = gruF + (size_t)(l*3+0)*G3*KP300;
        const _Float16* cwiF = gruF + (size_t)(l*3+1)*G3*KP300;
        const _Float16* cwhF = gruF + (size_t)(l*3+2)*G3*KP300;

        // GHp = Hin @ pwh^T + pbh
        gemm_mfma<<<dim3(15,36),256,0,stream>>>(Hbuf+hcol, HDIM, pwhF, KP300,
                                                gp_bhh + l*G3, bufA, G3, G3, DD, 0);
        // fused: scan (blocks 0..47) + GIc GEMM (blocks 48..587)
        scan_kernel<<<BB+GIC_TILES,1024,0,stream>>>(Hbuf, bufA, pwiQl, pwhQl,
                                          gp_bih + l*G3, gp_bhh + l*G3,
                                          gat_wk + l*DD, gat_wq + l*DD, gat_b, l,
                                          adj, Mbuf, ccol, hcol, pcol,
                                          cwiF, gc_bih + l*G3, bufB);
        // GHc = M @ cwh^T + cbh
        gemm_mfma<<<dim3(15,36),256,0,stream>>>(Mbuf, DD, cwhF, KP300,
                                                gc_bhh + l*G3, bufC, G3, G3, DD, 0);
        // CL = GRU-combine
        combine_c<<<ROWS,320,0,stream>>>(bufB, bufC, Mbuf, Hbuf, clcol);
    }

    // MLP
    gemm_mfma<<<dim3(5,36),256,0,stream>>>(Hbuf, HDIM, mlp0F, 3728, mlp_b0,
                                           bufB, DD, DD, HDIM, 1);
    gemm_mfma<<<dim3(5,36),256,0,stream>>>(bufB, DD, mlp1F, KP300, mlp_b1,
                                           bufC, DD, DD, DD, 1);
    logits_kernel<<<ROWS,64,0,stream>>>(bufC, mlp_w2, mlp_b2, out);
}

// Round 7
// 2622.438 us; speedup vs baseline: 1.2438x; 1.0206x over previous
//
#include <hip/hip_runtime.h>
#include <math.h>

#define BB 48
#define NN 96
#define EE 1024
#define DD 300
#define LL 4
#define G3 900          // 3*D
#define PP 150          // DD/2 f16 pairs
#define PP2 152         // padded pairs (38 chunks of 4)
#define NC4 38          // weight chunks of 4 pairs
#define HDIM 3724       // D*(2L+1)+E
#define ROWS (BB*NN)    // 4608
#define NEGI -1.0e30f
#define KP300 304       // 300 padded to mult-of-8
#define GIC_TILES 540   // 15 x 36 tiles for fused GIc GEMM

#define NLDS 6          // pwi chunks resident in LDS (86400 B), ids 0..5
#define NPIN 14         // pwi chunks pinned in regs (56), ids 6..19
// streamed chunks in phase D: 20..37 (18 chunks)

typedef _Float16 half2_t __attribute__((ext_vector_type(2)));
typedef _Float16 h8 __attribute__((ext_vector_type(8)));
typedef float f4 __attribute__((ext_vector_type(4)));

__device__ __forceinline__ float sigm(float x){
    return __fdividef(1.0f, 1.0f + __expf(-x));
}
__device__ __forceinline__ float ftanh(float x){
    float e = __expf(2.0f*x);
    return 1.0f - __fdividef(2.0f, e + 1.0f);
}

__device__ __forceinline__ void dot4(const h8 wv, const h8 mc,
                                     float& a0, float& a1, float& a2, float& a3)
{
    half2_t w0,w1,w2,w3,m0,m1,m2,m3;
    w0.x=wv[0]; w0.y=wv[1]; m0.x=mc[0]; m0.y=mc[1];
    w1.x=wv[2]; w1.y=wv[3]; m1.x=mc[2]; m1.y=mc[3];
    w2.x=wv[4]; w2.y=wv[5]; m2.x=mc[4]; m2.y=mc[5];
    w3.x=wv[6]; w3.y=wv[7]; m3.x=mc[6]; m3.y=mc[7];
    a0 = __builtin_amdgcn_fdot2(w0, m0, a0, false);
    a1 = __builtin_amdgcn_fdot2(w1, m1, a1, false);
    a2 = __builtin_amdgcn_fdot2(w2, m2, a2, false);
    a3 = __builtin_amdgcn_fdot2(w3, m3, a3, false);
}

// ---------------- pack W (L,900,300) -> coalesced h8 chunks (L,38,900) ----------------
__global__ __launch_bounds__(256) void pack_w_q(const float* __restrict__ src_all,
                                                h8* __restrict__ dst)
{
    int l = blockIdx.y;
    int idx = blockIdx.x*256 + threadIdx.x;
    if (idx >= NC4*G3) return;
    int c = idx / G3, gate = idx % G3;
    const float* src = src_all + (size_t)l*G3*DD + (size_t)gate*DD;
    h8 v;
    #pragma unroll
    for (int j=0;j<8;j++){
        int d = 8*c + j;
        v[j] = (d<DD) ? (_Float16)src[d] : (_Float16)0.f;
    }
    dst[(size_t)l*NC4*G3 + idx] = v;
}

// ---------------- GRU weights [900][300] fp32 -> [900][304] f16 (zero-padded) ----------------
__global__ __launch_bounds__(256) void conv_gru_w(const float* __restrict__ gp_whh,
                                                  const float* __restrict__ gc_wih,
                                                  const float* __restrict__ gc_whh,
                                                  _Float16* __restrict__ outp)
{
    int z = blockIdx.y; int l = z/3, wsel = z%3;
    const float* src = (wsel==0?gp_whh:wsel==1?gc_wih:gc_whh) + (size_t)l*G3*DD;
    _Float16* dst = outp + (size_t)z*G3*KP300;
    int idx = blockIdx.x*256 + threadIdx.x;
    if (idx >= G3*KP300) return;
    int n = idx/KP300, k = idx%KP300;
    dst[idx] = (k<DD) ? (_Float16)src[(size_t)n*DD+k] : (_Float16)0.f;
}

// ---------------- transpose-convert [K][N] fp32 -> [N][Kpad] f16 ----------------
__global__ __launch_bounds__(256) void convT(const float* __restrict__ src,
                                             _Float16* __restrict__ dst,
                                             int K, int N, int Kpad)
{
    int idx = blockIdx.x*256 + threadIdx.x;
    if (idx >= N*Kpad) return;
    int n = idx/Kpad, k = idx%Kpad;
    dst[idx] = (k<K) ? (_Float16)src[(size_t)k*N + n] : (_Float16)0.f;
}

// ---------------- MFMA f16 GEMM tile body (device fn, 256 active threads) ----------------
__device__ __forceinline__ void gemm_tile(
    int m0, int n0, int tid,
    const float* __restrict__ A, int lda,
    const _Float16* __restrict__ B, int Kpad,
    const float* __restrict__ bias,
    float* __restrict__ C, int ldc,
    int N, int K, int relu,
    _Float16 (*As)[40], _Float16 (*Bs)[40])
{
    int w = tid>>6, lane = tid&63;
    int wy = w>>1, wx = w&1;
    int lm = lane&15, q = lane>>4;

    f4 acc[4][2];
    #pragma unroll
    for (int a=0;a<4;a++)
        #pragma unroll
        for (int b=0;b<2;b++)
            #pragma unroll
            for (int r=0;r<4;r++) acc[a][b][r]=0.f;

    int am = tid>>1, akg = (tid&1)*16;
    int bn = tid>>2, bkg = (tid&3)*8;
    const float* arow = A + (size_t)(m0+am)*lda;

    for (int k0=0; k0<K; k0+=32){
        {
            __align__(16) _Float16 av[16];
            #pragma unroll
            for (int u=0;u<16;u+=4){
                int k = k0 + akg + u;
                float x0,x1,x2,x3;
                if (k+4 <= K){
                    float4 v = *(const float4*)(arow + k);
                    x0=v.x;x1=v.y;x2=v.z;x3=v.w;
                } else {
                    x0 = (k  <K)? arow[k  ]:0.f;
                    x1 = (k+1<K)? arow[k+1]:0.f;
                    x2 = (k+2<K)? arow[k+2]:0.f;
                    x3 = (k+3<K)? arow[k+3]:0.f;
                }
                av[u]=(_Float16)x0; av[u+1]=(_Float16)x1;
                av[u+2]=(_Float16)x2; av[u+3]=(_Float16)x3;
            }
            *(h8*)&As[am][akg]   = *(h8*)&av[0];
            *(h8*)&As[am][akg+8] = *(h8*)&av[8];
        }
        {
            int gk = k0 + bkg;
            h8 bv;
            #pragma unroll
            for (int j=0;j<8;j++) bv[j]=(_Float16)0.f;
            if (n0+bn < N && gk < Kpad)
                bv = *(const h8*)(B + (size_t)(n0+bn)*Kpad + gk);
            *(h8*)&Bs[bn][bkg] = bv;
        }
        __syncthreads();
        h8 af[4], bf[2];
        #pragma unroll
        for (int mb=0; mb<4; mb++) af[mb] = *(h8*)&As[wy*64+mb*16+lm][q*8];
        #pragma unroll
        for (int nb=0; nb<2; nb++) bf[nb] = *(h8*)&Bs[wx*32+nb*16+lm][q*8];
        #pragma unroll
        for (int mb=0; mb<4; mb++)
            #pragma unroll
            for (int nb=0; nb<2; nb++)
                acc[mb][nb] = __builtin_amdgcn_mfma_f32_16x16x32_f16(af[mb], bf[nb], acc[mb][nb], 0,0,0);
        __syncthreads();
    }
    #pragma unroll
    for (int mb=0; mb<4; mb++){
        int r0 = m0 + wy*64 + mb*16 + q*4;
        #pragma unroll
        for (int nb=0; nb<2; nb++){
            int c = n0 + wx*32 + nb*16 + lm;
            if (c < N){
                float bb = bias[c];
                #pragma unroll
                for (int reg=0; reg<4; reg++){
                    float v = acc[mb][nb][reg] + bb;
                    if (relu) v = fmaxf(v, 0.f);
                    C[(size_t)(r0+reg)*ldc + c] = v;
                }
            }
        }
    }
}

// ---------------- standalone MFMA GEMM kernel ----------------
__global__ __launch_bounds__(256) void gemm_mfma(
    const float* __restrict__ A, int lda,
    const _Float16* __restrict__ B, int Kpad,
    const float* __restrict__ bias,
    float* __restrict__ C, int ldc,
    int N, int K, int relu)
{
    __shared__ _Float16 As[128][40];
    __shared__ _Float16 Bs[64][40];
    gemm_tile(blockIdx.y*128, blockIdx.x*64, threadIdx.x,
              A, lda, B, Kpad, bias, C, ldc, N, K, relu, As, Bs);
}

// ---------------- copy features into last 1024 cols of Hbuf ----------------
__global__ void featcopy(const float* __restrict__ f, float* __restrict__ H)
{
    size_t row = blockIdx.x;
    int t = threadIdx.x;
    float4 v = *(const float4*)(f + row*EE + t*4);
    *(float4*)(H + row*HDIM + 2700 + t*4) = v;
}

// ---------------- fused scan + GIc GEMM ----------------
// blocks 0..47: sequential p-scan. blocks 48..587: GIc GEMM tiles.
// vs R6: phase-AB compacts the ACTIVE (j, e_j) pairs (ballot + popcount
// prefix) into an LDS float2 list; phase C iterates only nact ~= i/2 entries
// with a 4-way j-split (600 threads; prefetchers moved to t in [640,940)
// using float4). Weight residency unchanged: 6 LDS + 14 reg + 18 streamed.
__global__ void __launch_bounds__(1024)
__attribute__((amdgpu_waves_per_eu(4,4)))
scan_kernel(
    float* __restrict__ Hbuf,
    const float* __restrict__ GHp,
    const h8* __restrict__ pwiQ,          // (38,900) h8 chunks of pwi
    const h8* __restrict__ pwhQ,          // (38,900) h8 chunks of pwh (init)
    const float* __restrict__ pbi,
    const float* __restrict__ pbh,
    const float* __restrict__ wk,
    const float* __restrict__ wq,
    const float* __restrict__ gat_b, int lidx,
    const float* __restrict__ adj,
    float* __restrict__ Mbuf,
    int ccol, int hcol, int pcol,
    const _Float16* __restrict__ cwiF,
    const float* __restrict__ cbi,
    float* __restrict__ GIc)
{
    __shared__ __align__(16) char pool[160576];
    (void)wq; (void)gat_b; (void)lidx;   // q and gat_b cancel in softmax

    // ---- GEMM blocks (LDS pool reused as As/Bs) ----
    if (blockIdx.x >= BB){
        if (threadIdx.x < 256){
            _Float16 (*As)[40] = (_Float16 (*)[40])pool;
            _Float16 (*Bs)[40] = (_Float16 (*)[40])(pool + 128*40*2);
            int bid = blockIdx.x - BB;
            int n0 = (bid % 15)*64, m0 = (bid / 15)*128;
            gemm_tile(m0, n0, threadIdx.x, Hbuf + ccol, HDIM, cwiF, KP300,
                      cbi, GIc, G3, G3, DD, 0, As, Bs);
        }
        return;
    }

    int b = blockIdx.x;
    int t = threadIdx.x;

    // ---- LDS pool carve-up ----
    half2_t (*P_h2)[PP]   = (half2_t (*)[PP])(pool);             //      0: 57600
    h8*      Wlds         = (h8*)(pool + 57600);                 //  57600: 86400 (6 chunks)
    float*   g_s          = (float*)(pool + 144000);             // 144000:  3600
    float  (*Mpart)[DD]   = (float (*)[DD])(pool + 147600);      // 147600:  4800 (4 groups)
    float*   ghp_s        = (float*)(pool + 152400);             // 152400:  3600
    float*   hv_s         = (float*)(pool + 156000);             // 156000:  1200
    half2_t* M_h2         = (half2_t*)(pool + 157200);           // 157200:   640
    float*   pk_s         = (float*)(pool + 157840);             // 157840:   384
    float*   pksum        = (float*)(pool + 158224);             // 158224:    32
    float2*  cpair        = (float2*)(pool + 158256);            // 158256:   768 (idx,w)
    int*     ncnt_s       = (int*)(pool + 159024);               // 159024:    16
    unsigned (*adjb)[4]   = (unsigned (*)[4])(pool + 159040);    // 159040:  1536 -> 160576

    size_t rowbase = (size_t)b*NN;

    float pbi_r = (t < G3) ? pbi[t] : 0.f;
    float2 wk_r = make_float2(0.f,0.f);
    if (t < PP) wk_r = *(const float2*)&wk[2*t];

    // ---- one-time: 14 pinned weight chunks (ids 6..19), anti-remat anchored
    h8 wp0,wp1,wp2,wp3,wp4,wp5,wp6,wp7,wp8,wp9,wp10,wp11,wp12,wp13;
    if (t < G3){
        const h8* W = pwiQ + t;
        wp0 = W[(size_t)6*G3];   wp1 = W[(size_t)7*G3];   wp2 = W[(size_t)8*G3];
        wp3 = W[(size_t)9*G3];   wp4 = W[(size_t)10*G3];  wp5 = W[(size_t)11*G3];
        wp6 = W[(size_t)12*G3];  wp7 = W[(size_t)13*G3];  wp8 = W[(size_t)14*G3];
        wp9 = W[(size_t)15*G3];  wp10 = W[(size_t)16*G3]; wp11 = W[(size_t)17*G3];
        wp12 = W[(size_t)18*G3]; wp13 = W[(size_t)19*G3];
        asm volatile("" : "+v"(wp0),"+v"(wp1),"+v"(wp2),"+v"(wp3),
                          "+v"(wp4),"+v"(wp5),"+v"(wp6));
        asm volatile("" : "+v"(wp7),"+v"(wp8),"+v"(wp9),"+v"(wp10),
                          "+v"(wp11),"+v"(wp12),"+v"(wp13));
    }

    // ---- init phase 1: LDS weight chunks (0..5) + adj bitmask + Cin0 -> M
    for (int idx=t; idx<NLDS*G3; idx+=1024)
        Wlds[idx] = pwiQ[idx];
    if (t < NN*3){
        int r = t/3, w = t%3;
        const float* arow = adj + (rowbase + r)*NN + w*32;
        unsigned m = 0;
        for (int c=0;c<32;c++) if (arow[c] != 0.f) m |= (1u<<c);
        adjb[r][w] = m;
    }
    if (t < PP){
        float2 c2 = *(const float2*)&Hbuf[rowbase*HDIM + ccol + 2*t];
        Mpart[0][2*t] = c2.x; Mpart[0][2*t+1] = c2.y;
        half2_t mh; mh.x = (_Float16)c2.x; mh.y = (_Float16)c2.y;
        M_h2[t] = mh;
    } else if (t < PP2){
        half2_t z; z.x=(_Float16)0.f; z.y=(_Float16)0.f;
        M_h2[t] = z;
    }
    __syncthreads();
    // ---- init phase 2: gh0 = Cin0 @ pwh^T + pbh
    if (t < G3){
        const h8* W2 = pwhQ + t;
        float a0=0.f, a1=0.f, a2=0.f, a3=0.f;
        #pragma unroll 4
        for (int c=0;c<NC4;c++){
            h8 wv = W2[(size_t)c*G3];
            h8 mc = *(h8*)&M_h2[4*c];
            dot4(wv, mc, a0,a1,a2,a3);
        }
        g_s[t] = pbh[t] + (a0+a2) + (a1+a3);
    }
    __syncthreads();
    // ---- init phase 3: p0 = GRU(x=0, h=Cin0); pk partials; M[b,0]=0
    if (t < 192){
        float pw = 0.f;
        if (t < PP){
            int d0 = 2*t, d1 = 2*t+1;
            float r0  = sigm(pbi[d0]      + g_s[d0]);
            float z0  = sigm(pbi[DD+d0]   + g_s[DD+d0]);
            float n0  = ftanh(pbi[2*DD+d0] + r0*g_s[2*DD+d0]);
            float p0  = (1.f-z0)*n0 + z0*Mpart[0][d0];
            float r1  = sigm(pbi[d1]      + g_s[d1]);
            float z1  = sigm(pbi[DD+d1]   + g_s[DD+d1]);
            float n1  = ftanh(pbi[2*DD+d1] + r1*g_s[2*DD+d1]);
            float p1  = (1.f-z1)*n1 + z1*Mpart[0][d1];
            *(float2*)&Hbuf[rowbase*HDIM + pcol + d0] = make_float2(p0,p1);
            half2_t ph; ph.x = (_Float16)p0; ph.y = (_Float16)p1;
            P_h2[0][t] = ph;
            pw = p0*wk_r.x + p1*wk_r.y;
            *(float2*)&Mbuf[rowbase*DD + d0] = make_float2(0.f,0.f);
        }
        #pragma unroll
        for (int o=32;o>0;o>>=1) pw += __shfl_xor(pw,o);
        if ((t&63)==0) pksum[t>>6] = pw;
    }
    __syncthreads();

    float m_run = NEGI;   // running max of pk (uniform in wave 0)

    for (int i=1;i<NN;i++){
        size_t row = rowbase + i;
        // ---- AB (wave 0): softmax over pk + ACTIVE-LIST COMPACTION
        if (t < 64){
            float s_last = pksum[0]+pksum[1]+pksum[2];
            if (t==0) pk_s[i-1] = s_last;
            m_run = fmaxf(m_run, s_last);
            bool act0 = false, act1 = false;
            float a0 = NEGI, a1 = NEGI;
            if (t < i && ((adjb[i][t>>5]>>(t&31))&1u)){
                act0 = true;
                a0 = (t==i-1)? s_last : pk_s[t];
            }
            int j1 = 64+t;
            if (t < 32 && j1 < i && ((adjb[i][2]>>t)&1u)){
                act1 = true;
                a1 = (j1==i-1)? s_last : pk_s[j1];
            }
            float e0 = act0 ? __expf(a0 - m_run) : 0.f;
            float e1 = act1 ? __expf(a1 - m_run) : 0.f;
            float ss = e0+e1;
            #pragma unroll
            for (int o=32;o>0;o>>=1) ss += __shfl_xor(ss,o);
            float inv = __fdividef(1.f, ss);
            unsigned long long mask0 = __ballot(act0);
            unsigned long long mask1 = __ballot(act1);
            unsigned long long lt = (1ull<<t)-1ull;   // t<64 here
            int base = __popcll(mask0);
            if (act0){
                int pos0 = __popcll(mask0 & lt);
                cpair[pos0] = make_float2(__int_as_float(t), e0*inv);
            }
            if (act1){
                int pos1 = base + __popcll(mask1 & lt);
                cpair[pos1] = make_float2(__int_as_float(j1), e1*inv);
            }
            if (t==0) ncnt_s[0] = base + __popcll(mask1);
        }
        __syncthreads();
        // ---- C (t<600): 4-way j-split over COMPACTED list; prefetch (t 640..939)
        if (t < 600){
            int nact = ncnt_s[0];
            int g = t/150, dp = t%150;
            int cnt = (nact+3)>>2;
            int j0 = g*cnt; int jend = j0+cnt; if (jend > nact) jend = nact;
            float m0=0.f, m1=0.f;
            #pragma unroll 4
            for (int jj=j0;jj<jend;jj++){
                float2 pr = cpair[jj];
                int j = __float_as_int(pr.x);
                half2_t pv = P_h2[j][dp];
                m0 += pr.y*(float)pv.x;
                m1 += pr.y*(float)pv.y;
            }
            *(float2*)&Mpart[g][2*dp] = make_float2(m0,m1);
        } else if (t >= 640 && t < 940){
            int idx = t-640;
            if (idx < 225)
                *(float4*)&ghp_s[idx*4] = *(const float4*)&GHp[row*G3 + idx*4];
            else {
                int h = idx-225;
                *(float4*)&hv_s[h*4] = *(const float4*)&Hbuf[row*HDIM + hcol + h*4];
            }
        }
        __syncthreads();
        // ---- Csum (t<150): combine 4 partials, write Mbuf + f16 M
        if (t < PP){
            float m0 = Mpart[0][2*t]+Mpart[1][2*t]+Mpart[2][2*t]+Mpart[3][2*t];
            float m1 = Mpart[0][2*t+1]+Mpart[1][2*t+1]+Mpart[2][2*t+1]+Mpart[3][2*t+1];
            half2_t mh; mh.x = (_Float16)m0; mh.y = (_Float16)m1;
            M_h2[t] = mh;
            *(float2*)&Mbuf[row*DD + 2*t] = make_float2(m0,m1);
        }
        __syncthreads();
        // ---- D (t<900): g = M @ pwi^T + pbi; 6 LDS + 14 pinned + 18 streamed
        if (t < G3){
            const h8* W = pwiQ + t;
            const h8* Mc = (const h8*)M_h2;
            float a0=0.f, a1=0.f, a2=0.f, a3=0.f;
            dot4(Wlds[t],        Mc[0], a0,a1,a2,a3);
            dot4(Wlds[G3+t],     Mc[1], a0,a1,a2,a3);
            dot4(Wlds[2*G3+t],   Mc[2], a0,a1,a2,a3);
            dot4(Wlds[3*G3+t],   Mc[3], a0,a1,a2,a3);
            dot4(Wlds[4*G3+t],   Mc[4], a0,a1,a2,a3);
            dot4(Wlds[5*G3+t],   Mc[5], a0,a1,a2,a3);
            dot4(wp0,  Mc[6],  a0,a1,a2,a3);
            dot4(wp1,  Mc[7],  a0,a1,a2,a3);
            dot4(wp2,  Mc[8],  a0,a1,a2,a3);
            dot4(wp3,  Mc[9],  a0,a1,a2,a3);
            dot4(wp4,  Mc[10], a0,a1,a2,a3);
            dot4(wp5,  Mc[11], a0,a1,a2,a3);
            dot4(wp6,  Mc[12], a0,a1,a2,a3);
            dot4(wp7,  Mc[13], a0,a1,a2,a3);
            dot4(wp8,  Mc[14], a0,a1,a2,a3);
            dot4(wp9,  Mc[15], a0,a1,a2,a3);
            dot4(wp10, Mc[16], a0,a1,a2,a3);
            dot4(wp11, Mc[17], a0,a1,a2,a3);
            dot4(wp12, Mc[18], a0,a1,a2,a3);
            dot4(wp13, Mc[19], a0,a1,a2,a3);
            #pragma unroll 6
            for (int c=NLDS+NPIN;c<NC4;c++){
                h8 wv = W[(size_t)c*G3];
                dot4(wv, Mc[c], a0,a1,a2,a3);
            }
            g_s[t] = pbi_r + (a0+a2) + (a1+a3);
        }
        __syncthreads();
        // ---- E (t<192): GRU + pk partials
        if (t < 192){
            float pw = 0.f;
            if (t < PP){
                int d0 = 2*t, d1 = 2*t+1;
                float2 hv = *(const float2*)&hv_s[d0];
                float r0  = sigm(g_s[d0]      + ghp_s[d0]);
                float z0  = sigm(g_s[DD+d0]   + ghp_s[DD+d0]);
                float n0  = ftanh(g_s[2*DD+d0] + r0*ghp_s[2*DD+d0]);
                float p0  = (1.f-z0)*n0 + z0*hv.x;
                float r1  = sigm(g_s[d1]      + ghp_s[d1]);
                float z1  = sigm(g_s[DD+d1]   + ghp_s[DD+d1]);
                float n1  = ftanh(g_s[2*DD+d1] + r1*ghp_s[2*DD+d1]);
                float p1  = (1.f-z1)*n1 + z1*hv.y;
                *(float2*)&Hbuf[row*HDIM + pcol + d0] = make_float2(p0,p1);
                half2_t ph; ph.x = (_Float16)p0; ph.y = (_Float16)p1;
                P_h2[i][t] = ph;
                pw = p0*wk_r.x + p1*wk_r.y;
            }
            #pragma unroll
            for (int o=32;o>0;o>>=1) pw += __shfl_xor(pw,o);
            if ((t&63)==0) pksum[t>>6] = pw;
        }
        __syncthreads();
    }
}

// ---------------- c-side elementwise combine ----------------
__global__ __launch_bounds__(320) void combine_c(
    const float* __restrict__ GIc, const float* __restrict__ GHc,
    const float* __restrict__ Mbuf, float* __restrict__ Hbuf, int clcol)
{
    size_t row = blockIdx.x;
    int d = threadIdx.x;
    if (d < DD){
        float ir = GIc[row*G3+d], iz = GIc[row*G3+DD+d], inn = GIc[row*G3+2*DD+d];
        float hr = GHc[row*G3+d], hz = GHc[row*G3+DD+d], hn  = GHc[row*G3+2*DD+d];
        float r  = sigm(ir+hr);
        float z  = sigm(iz+hz);
        float nn = ftanh(inn + r*hn);
        float h  = Mbuf[row*DD+d];
        Hbuf[row*HDIM + clcol + d] = (1.f-z)*nn + z*h;
    }
}

// ---------------- logits: out = x2 @ w2 + b2 (N=7) ----------------
__global__ __launch_bounds__(64) void logits_kernel(
    const float* __restrict__ x2, const float* __restrict__ w2,
    const float* __restrict__ b2, float* __restrict__ out)
{
    size_t row = blockIdx.x;
    int lane = threadIdx.x;
    float acc[7]={0,0,0,0,0,0,0};
    for (int d=lane; d<DD; d+=64){
        float x = x2[row*DD+d];
        #pragma unroll
        for (int c=0;c<7;c++) acc[c] += x*w2[d*7+c];
    }
    #pragma unroll
    for (int c=0;c<7;c++){
        float s = acc[c];
        #pragma unroll
        for (int o=32;o>0;o>>=1) s += __shfl_down(s,o);
        if (lane==0) out[row*7+c] = s + b2[c];
    }
}

extern "C" void kernel_launch(void* const* d_in, const int* in_sizes, int n_in,
                              void* d_out, int out_size, void* d_ws, size_t ws_size,
                              hipStream_t stream)
{
    const float* features = (const float*)d_in[0];
    const float* adj      = (const float*)d_in[1];
    const float* fc1_w    = (const float*)d_in[3];
    const float* fc1_b    = (const float*)d_in[4];
    const float* gc_wih   = (const float*)d_in[5];
    const float* gc_whh   = (const float*)d_in[6];
    const float* gc_bih   = (const float*)d_in[7];
    const float* gc_bhh   = (const float*)d_in[8];
    const float* gp_wih   = (const float*)d_in[9];
    const float* gp_whh   = (const float*)d_in[10];
    const float* gp_bih   = (const float*)d_in[11];
    const float* gp_bhh   = (const float*)d_in[12];
    const float* gat_wq   = (const float*)d_in[13];
    const float* gat_wk   = (const float*)d_in[14];
    const float* gat_b    = (const float*)d_in[15];
    const float* mlp_w0   = (const float*)d_in[16];
    const float* mlp_b0   = (const float*)d_in[17];
    const float* mlp_w1   = (const float*)d_in[18];
    const float* mlp_b1   = (const float*)d_in[19];
    const float* mlp_w2   = (const float*)d_in[20];
    const float* mlp_b2   = (const float*)d_in[21];
    float* out = (float*)d_out;

    float* ws = (float*)d_ws;
    size_t off = 0;
    float* Hbuf = ws + off; off += (size_t)ROWS*HDIM;
    float* bufA = ws + off; off += (size_t)ROWS*G3;    // GHp
    float* bufB = ws + off; off += (size_t)ROWS*G3;    // GIc / x1
    float* bufC = ws + off; off += (size_t)ROWS*G3;    // GHc / x2
    float* Mbuf = ws + off; off += (size_t)ROWS*DD;
    h8* pwiQ = (h8*)(ws + off); off += (size_t)LL*NC4*G3*4;
    h8* pwhQ = (h8*)(ws + off); off += (size_t)LL*NC4*G3*4;
    _Float16* gruF = (_Float16*)(ws + off); off += (size_t)12*G3*KP300/2;
    _Float16* fc1F = (_Float16*)(ws + off); off += (size_t)DD*EE/2;
    _Float16* mlp0F= (_Float16*)(ws + off); off += (size_t)DD*3728/2;
    _Float16* mlp1F= (_Float16*)(ws + off); off += (size_t)DD*KP300/2;
    (void)ws_size; (void)in_sizes; (void)n_in; (void)out_size;

    // 1. weight prep
    {
        pack_w_q<<<dim3((NC4*G3+255)/256, LL), 256, 0, stream>>>(gp_wih, pwiQ);
        pack_w_q<<<dim3((NC4*G3+255)/256, LL), 256, 0, stream>>>(gp_whh, pwhQ);
        conv_gru_w<<<dim3((G3*KP300+255)/256, 12), 256, 0, stream>>>(gp_whh, gc_wih, gc_whh, gruF);
        convT<<<(DD*EE+255)/256, 256, 0, stream>>>(fc1_w, fc1F, EE, DD, EE);
        convT<<<(DD*3728+255)/256, 256, 0, stream>>>(mlp_w0, mlp0F, HDIM, DD, 3728);
        convT<<<(DD*KP300+255)/256, 256, 0, stream>>>(mlp_w1, mlp1F, DD, DD, KP300);
    }
    // 2. H0 = relu(features @ fc1_w + fc1_b) -> Hbuf col 0
    gemm_mfma<<<dim3(5,36),256,0,stream>>>(features, EE, fc1F, EE, fc1_b,
                                           Hbuf, HDIM, DD, EE, 1);
    // 3. features -> Hbuf cols [2700,3724)
    featcopy<<<ROWS,256,0,stream>>>(features, Hbuf);

    for (int l=0;l<LL;l++){
        int ccol  = (l==0)? 0 : 300 + (l-1)*600;
        int hcol  = l*300;
        int pcol  = 600 + l*600;
        int clcol = 300 + l*600;
        const h8* pwiQl = pwiQ + (size_t)l*NC4*G3;
        const h8* pwhQl = pwhQ + (size_t)l*NC4*G3;
        const _Float16* pwhF = gruF + (size_t)(l*3+0)*G3*KP300;
        const _Float16* cwiF = gruF + (size_t)(l*3+1)*G3*KP300;
        const _Float16* cwhF = gruF + (size_t)(l*3+2)*G3*KP300;

        // GHp = Hin @ pwh^T + pbh
        gemm_mfma<<<dim3(15,36),256,0,stream>>>(Hbuf+hcol, HDIM, pwhF, KP300,
                                                gp_bhh + l*G3, bufA, G3, G3, DD, 0);
        // fused: scan (blocks 0..47) + GIc GEMM (blocks 48..587)
        scan_kernel<<<BB+GIC_TILES,1024,0,stream>>>(Hbuf, bufA, pwiQl, pwhQl,
                                          gp_bih + l*G3, gp_bhh + l*G3,
                                          gat_wk + l*DD, gat_wq + l*DD, gat_b, l,
                                          adj, Mbuf, ccol, hcol, pcol,
                                          cwiF, gc_bih + l*G3, bufB);
        // GHc = M @ cwh^T + cbh
        gemm_mfma<<<dim3(15,36),256,0,stream>>>(Mbuf, DD, cwhF, KP300,
                                                gc_bhh + l*G3, bufC, G3, G3, DD, 0);
        // CL = GRU-combine
        combine_c<<<ROWS,320,0,stream>>>(bufB, bufC, Mbuf, Hbuf, clcol);
    }

    // MLP
    gemm_mfma<<<dim3(5,36),256,0,stream>>>(Hbuf, HDIM, mlp0F, 3728, mlp_b0,
                                           bufB, DD, DD, HDIM, 1);
    gemm_mfma<<<dim3(5,36),256,0,stream>>>(bufB, DD, mlp1F, KP300, mlp_b1,
                                           bufC, DD, DD, DD, 1);
    logits_kernel<<<ROWS,64,0,stream>>>(bufC, mlp_w2, mlp_b2, out);
}